// Round 2
// baseline (415.293 us; speedup 1.0000x reference)
//
#include <hip/hip_runtime.h>
#include <hip/hip_bf16.h>
#include <math.h>

typedef __bf16 bf16;
typedef __bf16 bf16x8 __attribute__((ext_vector_type(8)));
typedef __bf16 bf16x4 __attribute__((ext_vector_type(4)));
typedef float f32x4 __attribute__((ext_vector_type(4)));

#define T_SEQ 1024
#define NH 16
#define HD 64
#define DM 1024

__device__ __forceinline__ f32x4 mfma16(bf16x8 a, bf16x8 b, f32x4 c) {
  return __builtin_amdgcn_mfma_f32_16x16x32_bf16(a, b, c, 0, 0, 0);
}

__device__ __forceinline__ void gl_lds16(const bf16* g, bf16* l) {
  __builtin_amdgcn_global_load_lds(
      (const __attribute__((address_space(1))) void*)(g),
      (__attribute__((address_space(3))) void*)(l), 16, 0, 0);
}

// ---------------- bias table: table[h][d], d = i-j in [0,1023] ----------------
__global__ void hope_bias_kernel(const float* __restrict__ pi, float* __restrict__ table) {
  int idx = blockIdx.x * blockDim.x + threadIdx.x;  // 0..16383
  if (idx >= 1024 * NH) return;
  int h = idx >> 10, d = idx & 1023;
  float s = 0.f;
  if (h < 8) {
    int p0 = h * 32;
    for (int t = 0; t < 32; ++t) {
      // f = 10000^(-(p0+t)/512) = exp(-(p0+t) * ln(10000)/512)
      float f = expf(-(float)(p0 + t) * (9.210340371976184f / 512.0f));
      float theta = (float)d * f;
      s += cosf(theta) + sinf(theta);
    }
  } else {
    int p0 = (h - 8) * 32;
    for (int t = 0; t < 32; ++t)
      s += pi[(p0 + t) * 2] + pi[(p0 + t) * 2 + 1];
  }
  table[h * 1024 + d] = s;
}

// ---------------- f32 -> bf16 convert (vectorized) ----------------
__global__ void cvt_kernel(const float* __restrict__ in, bf16* __restrict__ out, int n) {
  int i = (blockIdx.x * blockDim.x + threadIdx.x) * 4;
  if (i < n) {
    float4 v = *reinterpret_cast<const float4*>(in + i);
    bf16x4 o;
    o[0] = (bf16)v.x; o[1] = (bf16)v.y; o[2] = (bf16)v.z; o[3] = (bf16)v.w;
    *reinterpret_cast<bf16x4*>(out + i) = o;
  }
}

// ---------------- shared GEMM mainloop (m97 style: global_load_lds) ----------------
// C[m,n] = sum_k A[m,k]*Bt[n,k]; 128x128 tile, BK=64, 4 waves, linear LDS [128][64]
__device__ __forceinline__ void gemm_tile_gl(
    const bf16* __restrict__ A, const bf16* __restrict__ Bt,
    int Kdim, int lda, int ldb, int m0, int n0,
    bf16* As, bf16* Bs, f32x4 acc[4][4], int tid)
{
  const int lane = tid & 63;
  const int wave = tid >> 6;
  const int wmv = (wave >> 1) * 64;
  const int wnv = (wave & 1) * 64;
  const int g = lane >> 4, lr = lane & 15;
  const int ldrow = lane >> 3;          // 0..7 within 8-row chunk
  const int ldcol = (lane & 7) * 8;     // element col

  for (int k0 = 0; k0 < Kdim; k0 += 64) {
#pragma unroll
    for (int c = 0; c < 4; ++c) {
      const int rbase = wave * 32 + c * 8;
      gl_lds16(&A[(size_t)(m0 + rbase + ldrow) * lda + k0 + ldcol], &As[rbase * 64]);
      gl_lds16(&Bt[(size_t)(n0 + rbase + ldrow) * ldb + k0 + ldcol], &Bs[rbase * 64]);
    }
    __syncthreads();
#pragma unroll
    for (int kk = 0; kk < 2; ++kk) {
      bf16x8 aF[4], bF[4];
#pragma unroll
      for (int mi = 0; mi < 4; ++mi)
        aF[mi] = *reinterpret_cast<const bf16x8*>(&As[(wmv + mi * 16 + lr) * 64 + kk * 32 + g * 8]);
#pragma unroll
      for (int ni = 0; ni < 4; ++ni)
        bF[ni] = *reinterpret_cast<const bf16x8*>(&Bs[(wnv + ni * 16 + lr) * 64 + kk * 32 + g * 8]);
#pragma unroll
      for (int mi = 0; mi < 4; ++mi)
#pragma unroll
        for (int ni = 0; ni < 4; ++ni)
          acc[mi][ni] = mfma16(aF[mi], bF[ni], acc[mi][ni]);
    }
    __syncthreads();
  }
}

// ---------------- QKV projection: qkv[m,n] -> Q/K/Vt (bf16) ----------------
__global__ __launch_bounds__(256) void gemm_qkv_kernel(
    const bf16* __restrict__ xb, const bf16* __restrict__ wb,
    const float* __restrict__ bias,
    bf16* __restrict__ Q, bf16* __restrict__ K, bf16* __restrict__ Vt)
{
  __shared__ bf16 As[128 * 64];
  __shared__ bf16 Bs[128 * 64];
  f32x4 acc[4][4];
  f32x4 z = {0.f, 0.f, 0.f, 0.f};
#pragma unroll
  for (int i = 0; i < 4; ++i)
#pragma unroll
    for (int j = 0; j < 4; ++j) acc[i][j] = z;
  const int m0 = blockIdx.y * 128, n0 = blockIdx.x * 128;
  gemm_tile_gl(xb, wb, DM, DM, DM, m0, n0, As, Bs, acc, threadIdx.x);

  const int lane = threadIdx.x & 63, wave = threadIdx.x >> 6;
  const int wmv = (wave >> 1) * 64, wnv = (wave & 1) * 64;
  const int g = lane >> 4, lr = lane & 15;
#pragma unroll
  for (int mi = 0; mi < 4; ++mi) {
#pragma unroll
    for (int ni = 0; ni < 4; ++ni) {
      int col = n0 + wnv + ni * 16 + lr;
      int c3 = col >> 10, rem = col & 1023;
      int hh = rem >> 6, dd = rem & 63;
      float bv = bias[col];
#pragma unroll
      for (int r = 0; r < 4; ++r) {
        int row = m0 + wmv + mi * 16 + g * 4 + r;
        int bb = row >> 10, t = row & 1023;
        float v = acc[mi][ni][r] + bv;
        size_t bhh = (size_t)(bb * NH + hh);
        bf16 o = (bf16)v;
        if (c3 == 0)      Q[(bhh * T_SEQ + t) * HD + dd] = o;
        else if (c3 == 1) K[(bhh * T_SEQ + t) * HD + dd] = o;
        else              Vt[(bhh * HD + dd) * T_SEQ + t] = o;
      }
    }
  }
}

// ---------------- output projection: out = Ob @ wprojT + b ----------------
__global__ __launch_bounds__(256) void gemm_proj_kernel(
    const bf16* __restrict__ Ob, const bf16* __restrict__ wb,
    const float* __restrict__ bias, float* __restrict__ out)
{
  __shared__ bf16 As[128 * 64];
  __shared__ bf16 Bs[128 * 64];
  f32x4 acc[4][4];
  f32x4 z = {0.f, 0.f, 0.f, 0.f};
#pragma unroll
  for (int i = 0; i < 4; ++i)
#pragma unroll
    for (int j = 0; j < 4; ++j) acc[i][j] = z;
  const int m0 = blockIdx.y * 128, n0 = blockIdx.x * 128;
  gemm_tile_gl(Ob, wb, DM, DM, DM, m0, n0, As, Bs, acc, threadIdx.x);

  const int lane = threadIdx.x & 63, wave = threadIdx.x >> 6;
  const int wmv = (wave >> 1) * 64, wnv = (wave & 1) * 64;
  const int g = lane >> 4, lr = lane & 15;
#pragma unroll
  for (int mi = 0; mi < 4; ++mi) {
#pragma unroll
    for (int ni = 0; ni < 4; ++ni) {
      int col = n0 + wnv + ni * 16 + lr;
      float bv = bias[col];
#pragma unroll
      for (int r = 0; r < 4; ++r) {
        int row = m0 + wmv + mi * 16 + g * 4 + r;
        out[(size_t)row * DM + col] = acc[mi][ni][r] + bv;
      }
    }
  }
}

// ---------------- causal flash attention with HoPE bias ----------------
// grid: (qp=4, bh=128). block: 512 threads, 8 waves; wave owns 16 q-rows.
// Block processes Q-tiles ta=7-qp and tb=qp (paired => 9 tile-units/block, balanced).
__global__ __launch_bounds__(512, 4) void attn_kernel(
    const bf16* __restrict__ Q, const bf16* __restrict__ K,
    const bf16* __restrict__ Vt, const float* __restrict__ table,
    bf16* __restrict__ O)
{
  __shared__ bf16 Ks[128][72];
  __shared__ bf16 Vs[64][136];
  __shared__ bf16 Ps[128][136];
  __shared__ float tbl[1024];

  const int tid = threadIdx.x;
  const int lane = tid & 63;
  const int wave = tid >> 6;      // 0..7
  const int wm = wave * 16;
  const int g = lane >> 4;        // 0..3
  const int lr = lane & 15;
  const int qp = blockIdx.x;      // 0..3
  const int bh = blockIdx.y;
  const int h = bh & 15;
  const int b = bh >> 4;
  const int ta = 7 - qp, tb = qp;
  const int q0a = ta * 128, q0b = tb * 128;

  const bf16* Qp = Q + (size_t)bh * (T_SEQ * HD);
  const bf16* Kp = K + (size_t)bh * (T_SEQ * HD);
  const bf16* Vp = Vt + (size_t)bh * (HD * T_SEQ);

  for (int i = tid; i < 1024; i += 512) tbl[i] = table[h * 1024 + i];

  bf16x8 qfa[2], qfb[2];
#pragma unroll
  for (int kk = 0; kk < 2; ++kk) {
    qfa[kk] = *reinterpret_cast<const bf16x8*>(&Qp[(size_t)(q0a + wm + lr) * HD + kk * 32 + g * 8]);
    qfb[kk] = *reinterpret_cast<const bf16x8*>(&Qp[(size_t)(q0b + wm + lr) * HD + kk * 32 + g * 8]);
  }

  f32x4 oa[4], ob[4];
  float ma[4], la[4], mb[4], lb[4];
  f32x4 z = {0.f, 0.f, 0.f, 0.f};
#pragma unroll
  for (int i = 0; i < 4; ++i) {
    oa[i] = z; ob[i] = z;
    ma[i] = -INFINITY; la[i] = 0.f;
    mb[i] = -INFINITY; lb[i] = 0.f;
  }

  const int srow = tid >> 3, scol = (tid & 7) * 8;     // K staging
  const int vrow = tid >> 4, vcol = (tid & 15) * 8;    // V staging

  bf16x8 kreg[2], vreg[2];
  kreg[0] = *reinterpret_cast<const bf16x8*>(&Kp[(size_t)(srow) * HD + scol]);
  kreg[1] = *reinterpret_cast<const bf16x8*>(&Kp[(size_t)(64 + srow) * HD + scol]);
  vreg[0] = *reinterpret_cast<const bf16x8*>(&Vp[(size_t)(vrow) * T_SEQ + vcol]);
  vreg[1] = *reinterpret_cast<const bf16x8*>(&Vp[(size_t)(vrow + 32) * T_SEQ + vcol]);

  auto process = [&](const bf16x8* qf, f32x4* o, float* m_, float* l_, int q0, int kt) {
    f32x4 s[8];
#pragma unroll
    for (int ni = 0; ni < 8; ++ni) s[ni] = z;
    // S = Q K^T
#pragma unroll
    for (int ni = 0; ni < 8; ++ni) {
      bf16x8 kf0 = *reinterpret_cast<const bf16x8*>(&Ks[ni * 16 + lr][g * 8]);
      bf16x8 kf1 = *reinterpret_cast<const bf16x8*>(&Ks[ni * 16 + lr][32 + g * 8]);
      s[ni] = mfma16(qf[0], kf0, s[ni]);
      s[ni] = mfma16(qf[1], kf1, s[ni]);
    }
    const int ib = q0 + wm + g * 4;
    const int jb = kt * 128 + lr;
    const bool diag = (kt == (q0 >> 7));
    float pm[4] = {-INFINITY, -INFINITY, -INFINITY, -INFINITY};
#pragma unroll
    for (int ni = 0; ni < 8; ++ni) {
#pragma unroll
      for (int r = 0; r < 4; ++r) {
        int d = (ib + r) - (jb + ni * 16);
        int dc = d < 0 ? 0 : d;
        float v = s[ni][r] * 0.125f + tbl[dc];
        if (diag && d < 0) v = -INFINITY;
        s[ni][r] = v;
        pm[r] = fmaxf(pm[r], v);
      }
    }
#pragma unroll
    for (int r = 0; r < 4; ++r) {
#pragma unroll
      for (int off = 8; off >= 1; off >>= 1)
        pm[r] = fmaxf(pm[r], __shfl_xor(pm[r], off));
      float mnew = fmaxf(m_[r], pm[r]);
      float corr = __expf(m_[r] - mnew);
      m_[r] = mnew;
      float rs = 0.f;
#pragma unroll
      for (int ni = 0; ni < 8; ++ni) {
        float p = __expf(s[ni][r] - mnew);
        s[ni][r] = p;
        rs += p;
      }
#pragma unroll
      for (int off = 8; off >= 1; off >>= 1)
        rs += __shfl_xor(rs, off);
      l_[r] = l_[r] * corr + rs;
#pragma unroll
      for (int nd = 0; nd < 4; ++nd) o[nd][r] *= corr;
    }
    // P -> LDS (wave-private rows; within-wave ordering handles RAW)
#pragma unroll
    for (int ni = 0; ni < 8; ++ni)
#pragma unroll
      for (int r = 0; r < 4; ++r)
        Ps[wm + g * 4 + r][ni * 16 + lr] = (bf16)s[ni][r];
    // O += P @ V
#pragma unroll
    for (int kk = 0; kk < 4; ++kk) {
      bf16x8 pf = *reinterpret_cast<const bf16x8*>(&Ps[wm + lr][kk * 32 + g * 8]);
#pragma unroll
      for (int nd = 0; nd < 4; ++nd) {
        bf16x8 vf = *reinterpret_cast<const bf16x8*>(&Vs[nd * 16 + lr][kk * 32 + g * 8]);
        o[nd] = mfma16(pf, vf, o[nd]);
      }
    }
  };

  const int nkt = 8 - qp;
  for (int kt = 0; kt < nkt; ++kt) {
    __syncthreads();   // prior iter's reads of Ks/Vs complete
    *reinterpret_cast<bf16x8*>(&Ks[srow][scol]) = kreg[0];
    *reinterpret_cast<bf16x8*>(&Ks[srow + 64][scol]) = kreg[1];
    *reinterpret_cast<bf16x8*>(&Vs[vrow][vcol]) = vreg[0];
    *reinterpret_cast<bf16x8*>(&Vs[vrow + 32][vcol]) = vreg[1];
    __syncthreads();
    if (kt + 1 < nkt) {  // async-issue next tile's loads; hide under compute
      const int kb = (kt + 1) * 128;
      kreg[0] = *reinterpret_cast<const bf16x8*>(&Kp[(size_t)(kb + srow) * HD + scol]);
      kreg[1] = *reinterpret_cast<const bf16x8*>(&Kp[(size_t)(kb + 64 + srow) * HD + scol]);
      vreg[0] = *reinterpret_cast<const bf16x8*>(&Vp[(size_t)(vrow) * T_SEQ + kb + vcol]);
      vreg[1] = *reinterpret_cast<const bf16x8*>(&Vp[(size_t)(vrow + 32) * T_SEQ + kb + vcol]);
    }
    process(qfa, oa, ma, la, q0a, kt);
    if (kt <= tb) process(qfb, ob, mb, lb, q0b, kt);
  }

  // epilogue
#pragma unroll
  for (int r = 0; r < 4; ++r) {
    int trowa = q0a + wm + g * 4 + r;
    int trowb = q0b + wm + g * 4 + r;
    float inva = 1.0f / la[r];
    float invb = 1.0f / lb[r];
#pragma unroll
    for (int nd = 0; nd < 4; ++nd) {
      O[((size_t)(b * T_SEQ + trowa)) * DM + h * HD + nd * 16 + lr] = (bf16)(oa[nd][r] * inva);
      O[((size_t)(b * T_SEQ + trowb)) * DM + h * HD + nd * 16 + lr] = (bf16)(ob[nd][r] * invb);
    }
  }
}

extern "C" void kernel_launch(void* const* d_in, const int* in_sizes, int n_in,
                              void* d_out, int out_size, void* d_ws, size_t ws_size,
                              hipStream_t stream) {
  const float* x      = (const float*)d_in[0];  // [8,1024,1024]
  const float* w_qkv  = (const float*)d_in[1];  // [3072,1024]
  const float* b_qkv  = (const float*)d_in[2];  // [3072]
  const float* w_proj = (const float*)d_in[3];  // [1024,1024]
  const float* b_proj = (const float*)d_in[4];  // [1024]
  const float* pos_in = (const float*)d_in[5];  // [256,2]
  float* out = (float*)d_out;

  char* ws = (char*)d_ws;
  bf16* xb     = (bf16*)(ws);                         // 16,777,216 B (reused as Ob)
  bf16* wqkvb  = (bf16*)(ws + 16777216);              //  6,291,456 B
  bf16* wprojb = (bf16*)(ws + 23068672);              //  2,097,152 B
  bf16* Qb     = (bf16*)(ws + 25165824);              // 16,777,216 B
  bf16* Kb     = (bf16*)(ws + 41943040);              // 16,777,216 B
  bf16* Vtb    = (bf16*)(ws + 58720256);              // 16,777,216 B
  float* table = (float*)(ws + 75497472);             //     65,536 B
  bf16* Ob = xb;  // attention output reuses xb (dead after gemm_qkv)

  hope_bias_kernel<<<64, 256, 0, stream>>>(pos_in, table);
  cvt_kernel<<<8192, 256, 0, stream>>>(x, xb, 8 * T_SEQ * DM);
  cvt_kernel<<<3072, 256, 0, stream>>>(w_qkv, wqkvb, 3 * DM * DM);
  cvt_kernel<<<1024, 256, 0, stream>>>(w_proj, wprojb, DM * DM);

  gemm_qkv_kernel<<<dim3(24, 64), 256, 0, stream>>>(xb, wqkvb, b_qkv, Qb, Kb, Vtb);
  attn_kernel<<<dim3(4, 128), 512, 0, stream>>>(Qb, Kb, Vtb, table, Ob);
  gemm_proj_kernel<<<dim3(8, 64), 256, 0, stream>>>(Ob, wprojb, b_proj, out);
}

// Round 3
// 227.841 us; speedup vs baseline: 1.8227x; 1.8227x over previous
//
#include <hip/hip_runtime.h>
#include <hip/hip_bf16.h>
#include <math.h>

typedef __bf16 bf16;
typedef __bf16 bf16x8 __attribute__((ext_vector_type(8)));
typedef __bf16 bf16x4 __attribute__((ext_vector_type(4)));
typedef float f32x4 __attribute__((ext_vector_type(4)));

#define T_SEQ 1024
#define NH 16
#define HD 64
#define DM 1024

__device__ __forceinline__ f32x4 mfma16(bf16x8 a, bf16x8 b, f32x4 c) {
  return __builtin_amdgcn_mfma_f32_16x16x32_bf16(a, b, c, 0, 0, 0);
}

__device__ __forceinline__ void gl_lds16(const bf16* g, bf16* l) {
  __builtin_amdgcn_global_load_lds(
      (const __attribute__((address_space(1))) void*)(g),
      (__attribute__((address_space(3))) void*)(l), 16, 0, 0);
}

// ---------------- bias table: table[h][d], d = i-j in [0,1023] ----------------
__global__ void hope_bias_kernel(const float* __restrict__ pi, float* __restrict__ table) {
  int idx = blockIdx.x * blockDim.x + threadIdx.x;  // 0..16383
  if (idx >= 1024 * NH) return;
  int h = idx >> 10, d = idx & 1023;
  float s = 0.f;
  if (h < 8) {
    int p0 = h * 32;
    for (int t = 0; t < 32; ++t) {
      float f = expf(-(float)(p0 + t) * (9.210340371976184f / 512.0f));
      float theta = (float)d * f;
      s += cosf(theta) + sinf(theta);
    }
  } else {
    int p0 = (h - 8) * 32;
    for (int t = 0; t < 32; ++t)
      s += pi[(p0 + t) * 2] + pi[(p0 + t) * 2 + 1];
  }
  table[h * 1024 + d] = s;
}

// ---------------- f32 -> bf16 convert (vectorized) ----------------
__global__ void cvt_kernel(const float* __restrict__ in, bf16* __restrict__ out, int n) {
  int i = (blockIdx.x * blockDim.x + threadIdx.x) * 4;
  if (i < n) {
    float4 v = *reinterpret_cast<const float4*>(in + i);
    bf16x4 o;
    o[0] = (bf16)v.x; o[1] = (bf16)v.y; o[2] = (bf16)v.z; o[3] = (bf16)v.w;
    *reinterpret_cast<bf16x4*>(out + i) = o;
  }
}

// ---------------- shared GEMM mainloop (m97 style: global_load_lds) ----------------
__device__ __forceinline__ void gemm_tile_gl(
    const bf16* __restrict__ A, const bf16* __restrict__ Bt,
    int Kdim, int lda, int ldb, int m0, int n0,
    bf16* As, bf16* Bs, f32x4 acc[4][4], int tid)
{
  const int lane = tid & 63;
  const int wave = tid >> 6;
  const int wmv = (wave >> 1) * 64;
  const int wnv = (wave & 1) * 64;
  const int g = lane >> 4, lr = lane & 15;
  const int ldrow = lane >> 3;
  const int ldcol = (lane & 7) * 8;

  for (int k0 = 0; k0 < Kdim; k0 += 64) {
#pragma unroll
    for (int c = 0; c < 4; ++c) {
      const int rbase = wave * 32 + c * 8;
      gl_lds16(&A[(size_t)(m0 + rbase + ldrow) * lda + k0 + ldcol], &As[rbase * 64]);
      gl_lds16(&Bt[(size_t)(n0 + rbase + ldrow) * ldb + k0 + ldcol], &Bs[rbase * 64]);
    }
    __syncthreads();
#pragma unroll
    for (int kk = 0; kk < 2; ++kk) {
      bf16x8 aF[4], bF[4];
#pragma unroll
      for (int mi = 0; mi < 4; ++mi)
        aF[mi] = *reinterpret_cast<const bf16x8*>(&As[(wmv + mi * 16 + lr) * 64 + kk * 32 + g * 8]);
#pragma unroll
      for (int ni = 0; ni < 4; ++ni)
        bF[ni] = *reinterpret_cast<const bf16x8*>(&Bs[(wnv + ni * 16 + lr) * 64 + kk * 32 + g * 8]);
#pragma unroll
      for (int mi = 0; mi < 4; ++mi)
#pragma unroll
        for (int ni = 0; ni < 4; ++ni)
          acc[mi][ni] = mfma16(aF[mi], bF[ni], acc[mi][ni]);
    }
    __syncthreads();
  }
}

// ---------------- QKV projection: qkv[m,n] -> Q/K/Vt (bf16) ----------------
__global__ __launch_bounds__(256) void gemm_qkv_kernel(
    const bf16* __restrict__ xb, const bf16* __restrict__ wb,
    const float* __restrict__ bias,
    bf16* __restrict__ Q, bf16* __restrict__ K, bf16* __restrict__ Vt)
{
  __shared__ bf16 As[128 * 64];
  __shared__ bf16 Bs[128 * 64];
  f32x4 acc[4][4];
  f32x4 z = {0.f, 0.f, 0.f, 0.f};
#pragma unroll
  for (int i = 0; i < 4; ++i)
#pragma unroll
    for (int j = 0; j < 4; ++j) acc[i][j] = z;
  const int m0 = blockIdx.y * 128, n0 = blockIdx.x * 128;
  gemm_tile_gl(xb, wb, DM, DM, DM, m0, n0, As, Bs, acc, threadIdx.x);

  const int lane = threadIdx.x & 63, wave = threadIdx.x >> 6;
  const int wmv = (wave >> 1) * 64, wnv = (wave & 1) * 64;
  const int g = lane >> 4, lr = lane & 15;
#pragma unroll
  for (int mi = 0; mi < 4; ++mi) {
#pragma unroll
    for (int ni = 0; ni < 4; ++ni) {
      int col = n0 + wnv + ni * 16 + lr;
      int c3 = col >> 10, rem = col & 1023;
      int hh = rem >> 6, dd = rem & 63;
      float bv = bias[col];
#pragma unroll
      for (int r = 0; r < 4; ++r) {
        int row = m0 + wmv + mi * 16 + g * 4 + r;
        int bb = row >> 10, t = row & 1023;
        float v = acc[mi][ni][r] + bv;
        size_t bhh = (size_t)(bb * NH + hh);
        bf16 o = (bf16)v;
        if (c3 == 0)      Q[(bhh * T_SEQ + t) * HD + dd] = o;
        else if (c3 == 1) K[(bhh * T_SEQ + t) * HD + dd] = o;
        else              Vt[(bhh * HD + dd) * T_SEQ + t] = o;
      }
    }
  }
}

// ---------------- output projection: out = Ob @ wprojT + b ----------------
__global__ __launch_bounds__(256) void gemm_proj_kernel(
    const bf16* __restrict__ Ob, const bf16* __restrict__ wb,
    const float* __restrict__ bias, float* __restrict__ out)
{
  __shared__ bf16 As[128 * 64];
  __shared__ bf16 Bs[128 * 64];
  f32x4 acc[4][4];
  f32x4 z = {0.f, 0.f, 0.f, 0.f};
#pragma unroll
  for (int i = 0; i < 4; ++i)
#pragma unroll
    for (int j = 0; j < 4; ++j) acc[i][j] = z;
  const int m0 = blockIdx.y * 128, n0 = blockIdx.x * 128;
  gemm_tile_gl(Ob, wb, DM, DM, DM, m0, n0, As, Bs, acc, threadIdx.x);

  const int lane = threadIdx.x & 63, wave = threadIdx.x >> 6;
  const int wmv = (wave >> 1) * 64, wnv = (wave & 1) * 64;
  const int g = lane >> 4, lr = lane & 15;
#pragma unroll
  for (int mi = 0; mi < 4; ++mi) {
#pragma unroll
    for (int ni = 0; ni < 4; ++ni) {
      int col = n0 + wnv + ni * 16 + lr;
      float bv = bias[col];
#pragma unroll
      for (int r = 0; r < 4; ++r) {
        int row = m0 + wmv + mi * 16 + g * 4 + r;
        out[(size_t)row * DM + col] = acc[mi][ni][r] + bv;
      }
    }
  }
}

// ---------------- causal flash attention with HoPE bias ----------------
// grid: (qp=4, bh=128). block: 512 threads, 8 waves; wave owns 16 q-rows.
// Block processes Q-tile 7-qp fully, THEN Q-tile qp (sequential => 1 live context,
// 9 tile-units per block => perfectly balanced grid of 512 blocks).
__global__ __launch_bounds__(512) void attn_kernel(
    const bf16* __restrict__ Q, const bf16* __restrict__ K,
    const bf16* __restrict__ Vt, const float* __restrict__ table,
    bf16* __restrict__ O)
{
  __shared__ bf16 Ks[128][72];
  __shared__ bf16 Vs[64][136];
  __shared__ bf16 Ps[128][136];
  __shared__ float tbl[1024];

  const int tid = threadIdx.x;
  const int lane = tid & 63;
  const int wave = tid >> 6;      // 0..7
  const int wm = wave * 16;
  const int g = lane >> 4;        // 0..3
  const int lr = lane & 15;
  const int qp = blockIdx.x;      // 0..3
  const int bh = blockIdx.y;
  const int h = bh & 15;
  const int b = bh >> 4;

  const bf16* Qp = Q + (size_t)bh * (T_SEQ * HD);
  const bf16* Kp = K + (size_t)bh * (T_SEQ * HD);
  const bf16* Vp = Vt + (size_t)bh * (HD * T_SEQ);

  for (int i = tid; i < 1024; i += 512) tbl[i] = table[h * 1024 + i];

  const int srow = tid >> 3, scol = (tid & 7) * 8;     // K staging
  const int vrow = tid >> 4, vcol = (tid & 15) * 8;    // V staging
  f32x4 z = {0.f, 0.f, 0.f, 0.f};

  for (int ph = 0; ph < 2; ++ph) {
    const int qt = ph ? qp : (7 - qp);
    const int q0 = qt * 128;
    const int nkt = qt + 1;

    bf16x8 qf[2];
#pragma unroll
    for (int kk = 0; kk < 2; ++kk)
      qf[kk] = *reinterpret_cast<const bf16x8*>(&Qp[(size_t)(q0 + wm + lr) * HD + kk * 32 + g * 8]);

    f32x4 o[4];
    float m_[4], l_[4];
#pragma unroll
    for (int i = 0; i < 4; ++i) { o[i] = z; m_[i] = -INFINITY; l_[i] = 0.f; }

    bf16x8 kreg[2], vreg[2];
    kreg[0] = *reinterpret_cast<const bf16x8*>(&Kp[(size_t)(srow) * HD + scol]);
    kreg[1] = *reinterpret_cast<const bf16x8*>(&Kp[(size_t)(64 + srow) * HD + scol]);
    vreg[0] = *reinterpret_cast<const bf16x8*>(&Vp[(size_t)(vrow) * T_SEQ + vcol]);
    vreg[1] = *reinterpret_cast<const bf16x8*>(&Vp[(size_t)(vrow + 32) * T_SEQ + vcol]);

    for (int kt = 0; kt < nkt; ++kt) {
      __syncthreads();   // prior iteration's (or prior phase's) LDS reads complete
      *reinterpret_cast<bf16x8*>(&Ks[srow][scol]) = kreg[0];
      *reinterpret_cast<bf16x8*>(&Ks[srow + 64][scol]) = kreg[1];
      *reinterpret_cast<bf16x8*>(&Vs[vrow][vcol]) = vreg[0];
      *reinterpret_cast<bf16x8*>(&Vs[vrow + 32][vcol]) = vreg[1];
      __syncthreads();
      if (kt + 1 < nkt) {  // prefetch next tile into regs; hides under compute
        const int kb = (kt + 1) * 128;
        kreg[0] = *reinterpret_cast<const bf16x8*>(&Kp[(size_t)(kb + srow) * HD + scol]);
        kreg[1] = *reinterpret_cast<const bf16x8*>(&Kp[(size_t)(kb + 64 + srow) * HD + scol]);
        vreg[0] = *reinterpret_cast<const bf16x8*>(&Vp[(size_t)(vrow) * T_SEQ + kb + vcol]);
        vreg[1] = *reinterpret_cast<const bf16x8*>(&Vp[(size_t)(vrow + 32) * T_SEQ + kb + vcol]);
      }

      // S = Q K^T
      f32x4 s[8];
#pragma unroll
      for (int ni = 0; ni < 8; ++ni) s[ni] = z;
#pragma unroll
      for (int ni = 0; ni < 8; ++ni) {
        bf16x8 kf0 = *reinterpret_cast<const bf16x8*>(&Ks[ni * 16 + lr][g * 8]);
        bf16x8 kf1 = *reinterpret_cast<const bf16x8*>(&Ks[ni * 16 + lr][32 + g * 8]);
        s[ni] = mfma16(qf[0], kf0, s[ni]);
        s[ni] = mfma16(qf[1], kf1, s[ni]);
      }

      // scale + bias + causal mask + online softmax
      const int ib = q0 + wm + g * 4;
      const int jb = kt * 128 + lr;
      const bool diag = (kt == qt);
      float pm[4] = {-INFINITY, -INFINITY, -INFINITY, -INFINITY};
#pragma unroll
      for (int ni = 0; ni < 8; ++ni) {
#pragma unroll
        for (int r = 0; r < 4; ++r) {
          int d = (ib + r) - (jb + ni * 16);
          int dc = d < 0 ? 0 : d;
          float v = s[ni][r] * 0.125f + tbl[dc];
          if (diag && d < 0) v = -INFINITY;
          s[ni][r] = v;
          pm[r] = fmaxf(pm[r], v);
        }
      }
#pragma unroll
      for (int r = 0; r < 4; ++r) {
#pragma unroll
        for (int off = 8; off >= 1; off >>= 1)
          pm[r] = fmaxf(pm[r], __shfl_xor(pm[r], off));
        float mnew = fmaxf(m_[r], pm[r]);
        float corr = __expf(m_[r] - mnew);
        m_[r] = mnew;
        float rs = 0.f;
#pragma unroll
        for (int ni = 0; ni < 8; ++ni) {
          float p = __expf(s[ni][r] - mnew);
          s[ni][r] = p;
          rs += p;
        }
#pragma unroll
        for (int off = 8; off >= 1; off >>= 1)
          rs += __shfl_xor(rs, off);
        l_[r] = l_[r] * corr + rs;
#pragma unroll
        for (int nd = 0; nd < 4; ++nd) o[nd][r] *= corr;
      }

      // P -> LDS (wave-private rows; within-wave ordering handles RAW)
#pragma unroll
      for (int ni = 0; ni < 8; ++ni)
#pragma unroll
        for (int r = 0; r < 4; ++r)
          Ps[wm + g * 4 + r][ni * 16 + lr] = (bf16)s[ni][r];

      // O += P @ V
#pragma unroll
      for (int kk = 0; kk < 4; ++kk) {
        bf16x8 pf = *reinterpret_cast<const bf16x8*>(&Ps[wm + lr][kk * 32 + g * 8]);
#pragma unroll
        for (int nd = 0; nd < 4; ++nd) {
          bf16x8 vf = *reinterpret_cast<const bf16x8*>(&Vs[nd * 16 + lr][kk * 32 + g * 8]);
          o[nd] = mfma16(pf, vf, o[nd]);
        }
      }
    }

    // epilogue for this phase
#pragma unroll
    for (int r = 0; r < 4; ++r) {
      int trow = q0 + wm + g * 4 + r;
      float inv = 1.0f / l_[r];
#pragma unroll
      for (int nd = 0; nd < 4; ++nd)
        O[((size_t)(b * T_SEQ + trow)) * DM + h * HD + nd * 16 + lr] = (bf16)(o[nd][r] * inv);
    }
  }
}

extern "C" void kernel_launch(void* const* d_in, const int* in_sizes, int n_in,
                              void* d_out, int out_size, void* d_ws, size_t ws_size,
                              hipStream_t stream) {
  const float* x      = (const float*)d_in[0];  // [8,1024,1024]
  const float* w_qkv  = (const float*)d_in[1];  // [3072,1024]
  const float* b_qkv  = (const float*)d_in[2];  // [3072]
  const float* w_proj = (const float*)d_in[3];  // [1024,1024]
  const float* b_proj = (const float*)d_in[4];  // [1024]
  const float* pos_in = (const float*)d_in[5];  // [256,2]
  float* out = (float*)d_out;

  char* ws = (char*)d_ws;
  bf16* xb     = (bf16*)(ws);                         // 16,777,216 B (reused as Ob)
  bf16* wqkvb  = (bf16*)(ws + 16777216);              //  6,291,456 B
  bf16* wprojb = (bf16*)(ws + 23068672);              //  2,097,152 B
  bf16* Qb     = (bf16*)(ws + 25165824);              // 16,777,216 B
  bf16* Kb     = (bf16*)(ws + 41943040);              // 16,777,216 B
  bf16* Vtb    = (bf16*)(ws + 58720256);              // 16,777,216 B
  float* table = (float*)(ws + 75497472);             //     65,536 B
  bf16* Ob = xb;  // attention output reuses xb (dead after gemm_qkv)

  hope_bias_kernel<<<64, 256, 0, stream>>>(pos_in, table);
  cvt_kernel<<<8192, 256, 0, stream>>>(x, xb, 8 * T_SEQ * DM);
  cvt_kernel<<<3072, 256, 0, stream>>>(w_qkv, wqkvb, 3 * DM * DM);
  cvt_kernel<<<1024, 256, 0, stream>>>(w_proj, wprojb, DM * DM);

  gemm_qkv_kernel<<<dim3(24, 64), 256, 0, stream>>>(xb, wqkvb, b_qkv, Qb, Kb, Vtb);
  attn_kernel<<<dim3(4, 128), 512, 0, stream>>>(Qb, Kb, Vtb, table, Ob);
  gemm_proj_kernel<<<dim3(8, 64), 256, 0, stream>>>(Ob, wprojb, b_proj, out);
}

// Round 4
// 211.086 us; speedup vs baseline: 1.9674x; 1.0794x over previous
//
#include <hip/hip_runtime.h>
#include <hip/hip_bf16.h>
#include <math.h>

typedef __bf16 bf16;
typedef __bf16 bf16x8 __attribute__((ext_vector_type(8)));
typedef __bf16 bf16x4 __attribute__((ext_vector_type(4)));
typedef float f32x4 __attribute__((ext_vector_type(4)));

#define T_SEQ 1024
#define NH 16
#define HD 64
#define DM 1024

__device__ __forceinline__ f32x4 mfma16(bf16x8 a, bf16x8 b, f32x4 c) {
  return __builtin_amdgcn_mfma_f32_16x16x32_bf16(a, b, c, 0, 0, 0);
}

__device__ __forceinline__ void gl_lds16(const bf16* g, bf16* l) {
  __builtin_amdgcn_global_load_lds(
      (const __attribute__((address_space(1))) void*)(g),
      (__attribute__((address_space(3))) void*)(l), 16, 0, 0);
}

// ---------------- bias table: table[h][d], d = i-j in [0,1023] ----------------
__global__ void hope_bias_kernel(const float* __restrict__ pi, float* __restrict__ table) {
  int idx = blockIdx.x * blockDim.x + threadIdx.x;  // 0..16383
  if (idx >= 1024 * NH) return;
  int h = idx >> 10, d = idx & 1023;
  float s = 0.f;
  if (h < 8) {
    int p0 = h * 32;
    for (int t = 0; t < 32; ++t) {
      float f = expf(-(float)(p0 + t) * (9.210340371976184f / 512.0f));
      float theta = (float)d * f;
      s += cosf(theta) + sinf(theta);
    }
  } else {
    int p0 = (h - 8) * 32;
    for (int t = 0; t < 32; ++t)
      s += pi[(p0 + t) * 2] + pi[(p0 + t) * 2 + 1];
  }
  table[h * 1024 + d] = s;
}

// ---------------- merged f32 -> bf16 convert for x, w_qkv, w_proj ----------------
__global__ void cvt3_kernel(const float* __restrict__ a, bf16* __restrict__ oa, int na,
                            const float* __restrict__ b, bf16* __restrict__ ob, int nb,
                            const float* __restrict__ c, bf16* __restrict__ oc, int nc) {
  int i = (blockIdx.x * blockDim.x + threadIdx.x) * 4;
  const float* src; bf16* dst; int off;
  if (i < na) { src = a; dst = oa; off = i; }
  else if (i < na + nb) { src = b; dst = ob; off = i - na; }
  else if (i < na + nb + nc) { src = c; dst = oc; off = i - na - nb; }
  else return;
  float4 v = *reinterpret_cast<const float4*>(src + off);
  bf16x4 o;
  o[0] = (bf16)v.x; o[1] = (bf16)v.y; o[2] = (bf16)v.z; o[3] = (bf16)v.w;
  *reinterpret_cast<bf16x4*>(dst + off) = o;
}

// ---------------- shared GEMM mainloop (m97 style: global_load_lds) ----------------
__device__ __forceinline__ void gemm_tile_gl(
    const bf16* __restrict__ A, const bf16* __restrict__ Bt,
    int Kdim, int lda, int ldb, int m0, int n0,
    bf16* As, bf16* Bs, f32x4 acc[4][4], int tid)
{
  const int lane = tid & 63;
  const int wave = tid >> 6;
  const int wmv = (wave >> 1) * 64;
  const int wnv = (wave & 1) * 64;
  const int g = lane >> 4, lr = lane & 15;
  const int ldrow = lane >> 3;
  const int ldcol = (lane & 7) * 8;

  for (int k0 = 0; k0 < Kdim; k0 += 64) {
#pragma unroll
    for (int c = 0; c < 4; ++c) {
      const int rbase = wave * 32 + c * 8;
      gl_lds16(&A[(size_t)(m0 + rbase + ldrow) * lda + k0 + ldcol], &As[rbase * 64]);
      gl_lds16(&Bt[(size_t)(n0 + rbase + ldrow) * ldb + k0 + ldcol], &Bs[rbase * 64]);
    }
    __syncthreads();
#pragma unroll
    for (int kk = 0; kk < 2; ++kk) {
      bf16x8 aF[4], bF[4];
#pragma unroll
      for (int mi = 0; mi < 4; ++mi)
        aF[mi] = *reinterpret_cast<const bf16x8*>(&As[(wmv + mi * 16 + lr) * 64 + kk * 32 + g * 8]);
#pragma unroll
      for (int ni = 0; ni < 4; ++ni)
        bF[ni] = *reinterpret_cast<const bf16x8*>(&Bs[(wnv + ni * 16 + lr) * 64 + kk * 32 + g * 8]);
#pragma unroll
      for (int mi = 0; mi < 4; ++mi)
#pragma unroll
        for (int ni = 0; ni < 4; ++ni)
          acc[mi][ni] = mfma16(aF[mi], bF[ni], acc[mi][ni]);
    }
    __syncthreads();
  }
}

// ---------------- QKV projection: qkv[m,n] -> Q/K/Vt (bf16) ----------------
// 1D grid 1536, XCD-chunked swizzle: each XCD gets 8 row-panels x 24 col-tiles,
// col-fastest -> A-panel stays in that XCD's L2 across its 24 column blocks.
__global__ __launch_bounds__(256) void gemm_qkv_kernel(
    const bf16* __restrict__ xb, const bf16* __restrict__ wb,
    const float* __restrict__ bias,
    bf16* __restrict__ Q, bf16* __restrict__ K, bf16* __restrict__ Vt)
{
  __shared__ bf16 As[128 * 64];
  __shared__ bf16 Bs[128 * 64];
  f32x4 acc[4][4];
  f32x4 z = {0.f, 0.f, 0.f, 0.f};
#pragma unroll
  for (int i = 0; i < 4; ++i)
#pragma unroll
    for (int j = 0; j < 4; ++j) acc[i][j] = z;
  const int wg = blockIdx.x;                 // 0..1535
  const int L = (wg & 7) * 192 + (wg >> 3);  // bijective: XCD chunking
  const int n0 = (L % 24) * 128;
  const int m0 = (L / 24) * 128;
  gemm_tile_gl(xb, wb, DM, DM, DM, m0, n0, As, Bs, acc, threadIdx.x);

  const int lane = threadIdx.x & 63, wave = threadIdx.x >> 6;
  const int wmv = (wave >> 1) * 64, wnv = (wave & 1) * 64;
  const int g = lane >> 4, lr = lane & 15;
  const int c3 = n0 >> 10;                   // uniform per block (n0 128-aligned)
  const int bb = m0 >> 10;                   // uniform (128-row tile never straddles)
#pragma unroll
  for (int mi = 0; mi < 4; ++mi) {
#pragma unroll
    for (int ni = 0; ni < 4; ++ni) {
      int col = n0 + wnv + ni * 16 + lr;
      int rem = col & 1023;
      int hh = rem >> 6, dd = rem & 63;
      float bv = bias[col];
      size_t bhh = (size_t)(bb * NH + hh);
      int t0 = (m0 & 1023) + wmv + mi * 16 + g * 4;
      if (c3 == 2) {
        bf16x4 pk;
#pragma unroll
        for (int r = 0; r < 4; ++r) pk[r] = (bf16)(acc[mi][ni][r] + bv);
        *reinterpret_cast<bf16x4*>(&Vt[(bhh * HD + dd) * T_SEQ + t0]) = pk;
      } else {
        bf16* dst = (c3 == 0) ? Q : K;
#pragma unroll
        for (int r = 0; r < 4; ++r)
          dst[(bhh * T_SEQ + t0 + r) * HD + dd] = (bf16)(acc[mi][ni][r] + bv);
      }
    }
  }
}

// ---------------- output projection: out = Ob @ wprojT + b ----------------
// 1D grid 512, XCD-chunked swizzle (each XCD: 8 row-panels x 8 col-tiles).
__global__ __launch_bounds__(256) void gemm_proj_kernel(
    const bf16* __restrict__ Ob, const bf16* __restrict__ wb,
    const float* __restrict__ bias, float* __restrict__ out)
{
  __shared__ bf16 As[128 * 64];
  __shared__ bf16 Bs[128 * 64];
  f32x4 acc[4][4];
  f32x4 z = {0.f, 0.f, 0.f, 0.f};
#pragma unroll
  for (int i = 0; i < 4; ++i)
#pragma unroll
    for (int j = 0; j < 4; ++j) acc[i][j] = z;
  const int wg = blockIdx.x;                // 0..511
  const int L = (wg & 7) * 64 + (wg >> 3);
  const int n0 = (L % 8) * 128;
  const int m0 = (L / 8) * 128;
  gemm_tile_gl(Ob, wb, DM, DM, DM, m0, n0, As, Bs, acc, threadIdx.x);

  const int lane = threadIdx.x & 63, wave = threadIdx.x >> 6;
  const int wmv = (wave >> 1) * 64, wnv = (wave & 1) * 64;
  const int g = lane >> 4, lr = lane & 15;
#pragma unroll
  for (int mi = 0; mi < 4; ++mi) {
#pragma unroll
    for (int ni = 0; ni < 4; ++ni) {
      int col = n0 + wnv + ni * 16 + lr;
      float bv = bias[col];
#pragma unroll
      for (int r = 0; r < 4; ++r) {
        int row = m0 + wmv + mi * 16 + g * 4 + r;
        out[(size_t)row * DM + col] = acc[mi][ni][r] + bv;
      }
    }
  }
}

// ---------------- causal flash attention with HoPE bias ----------------
__global__ __launch_bounds__(512) void attn_kernel(
    const bf16* __restrict__ Q, const bf16* __restrict__ K,
    const bf16* __restrict__ Vt, const float* __restrict__ table,
    bf16* __restrict__ O)
{
  __shared__ bf16 Ks[128][72];
  __shared__ bf16 Vs[64][136];
  __shared__ bf16 Ps[128][136];
  __shared__ float tbl[1024];

  const int tid = threadIdx.x;
  const int lane = tid & 63;
  const int wave = tid >> 6;      // 0..7
  const int wm = wave * 16;
  const int g = lane >> 4;        // 0..3
  const int lr = lane & 15;
  const int qp = blockIdx.x;      // 0..3
  const int bh = blockIdx.y;
  const int h = bh & 15;
  const int b = bh >> 4;

  const bf16* Qp = Q + (size_t)bh * (T_SEQ * HD);
  const bf16* Kp = K + (size_t)bh * (T_SEQ * HD);
  const bf16* Vp = Vt + (size_t)bh * (HD * T_SEQ);

  for (int i = tid; i < 1024; i += 512) tbl[i] = table[h * 1024 + i];

  const int srow = tid >> 3, scol = (tid & 7) * 8;     // K staging
  const int vrow = tid >> 4, vcol = (tid & 15) * 8;    // V staging
  f32x4 z = {0.f, 0.f, 0.f, 0.f};

  for (int ph = 0; ph < 2; ++ph) {
    const int qt = ph ? qp : (7 - qp);
    const int q0 = qt * 128;
    const int nkt = qt + 1;

    bf16x8 qf[2];
#pragma unroll
    for (int kk = 0; kk < 2; ++kk)
      qf[kk] = *reinterpret_cast<const bf16x8*>(&Qp[(size_t)(q0 + wm + lr) * HD + kk * 32 + g * 8]);

    f32x4 o[4];
    float m_[4], l_[4];
#pragma unroll
    for (int i = 0; i < 4; ++i) { o[i] = z; m_[i] = -INFINITY; l_[i] = 0.f; }

    bf16x8 kreg[2], vreg[2];
    kreg[0] = *reinterpret_cast<const bf16x8*>(&Kp[(size_t)(srow) * HD + scol]);
    kreg[1] = *reinterpret_cast<const bf16x8*>(&Kp[(size_t)(64 + srow) * HD + scol]);
    vreg[0] = *reinterpret_cast<const bf16x8*>(&Vp[(size_t)(vrow) * T_SEQ + vcol]);
    vreg[1] = *reinterpret_cast<const bf16x8*>(&Vp[(size_t)(vrow + 32) * T_SEQ + vcol]);

    for (int kt = 0; kt < nkt; ++kt) {
      __syncthreads();   // prior iteration's LDS reads complete
      *reinterpret_cast<bf16x8*>(&Ks[srow][scol]) = kreg[0];
      *reinterpret_cast<bf16x8*>(&Ks[srow + 64][scol]) = kreg[1];
      *reinterpret_cast<bf16x8*>(&Vs[vrow][vcol]) = vreg[0];
      *reinterpret_cast<bf16x8*>(&Vs[vrow + 32][vcol]) = vreg[1];
      __syncthreads();
      if (kt + 1 < nkt) {  // prefetch next tile into regs; hides under compute
        const int kb = (kt + 1) * 128;
        kreg[0] = *reinterpret_cast<const bf16x8*>(&Kp[(size_t)(kb + srow) * HD + scol]);
        kreg[1] = *reinterpret_cast<const bf16x8*>(&Kp[(size_t)(kb + 64 + srow) * HD + scol]);
        vreg[0] = *reinterpret_cast<const bf16x8*>(&Vp[(size_t)(vrow) * T_SEQ + kb + vcol]);
        vreg[1] = *reinterpret_cast<const bf16x8*>(&Vp[(size_t)(vrow + 32) * T_SEQ + kb + vcol]);
      }

      // S = Q K^T
      f32x4 s[8];
#pragma unroll
      for (int ni = 0; ni < 8; ++ni) s[ni] = z;
      __builtin_amdgcn_s_setprio(1);
#pragma unroll
      for (int ni = 0; ni < 8; ++ni) {
        bf16x8 kf0 = *reinterpret_cast<const bf16x8*>(&Ks[ni * 16 + lr][g * 8]);
        bf16x8 kf1 = *reinterpret_cast<const bf16x8*>(&Ks[ni * 16 + lr][32 + g * 8]);
        s[ni] = mfma16(qf[0], kf0, s[ni]);
        s[ni] = mfma16(qf[1], kf1, s[ni]);
      }
      __builtin_amdgcn_s_setprio(0);

      // scale + bias + causal mask + online softmax
      const int ib = q0 + wm + g * 4;
      const int jb = kt * 128 + lr;
      const bool diag = (kt == qt);
      float pm[4] = {-INFINITY, -INFINITY, -INFINITY, -INFINITY};
#pragma unroll
      for (int ni = 0; ni < 8; ++ni) {
#pragma unroll
        for (int r = 0; r < 4; ++r) {
          int d = (ib + r) - (jb + ni * 16);
          int dc = d < 0 ? 0 : d;
          float v = s[ni][r] * 0.125f + tbl[dc];
          if (diag && d < 0) v = -INFINITY;
          s[ni][r] = v;
          pm[r] = fmaxf(pm[r], v);
        }
      }
#pragma unroll
      for (int r = 0; r < 4; ++r) {
#pragma unroll
        for (int off = 8; off >= 1; off >>= 1)
          pm[r] = fmaxf(pm[r], __shfl_xor(pm[r], off));
        float mnew = fmaxf(m_[r], pm[r]);
        float corr = __expf(m_[r] - mnew);
        m_[r] = mnew;
        float rs = 0.f;
#pragma unroll
        for (int ni = 0; ni < 8; ++ni) {
          float p = __expf(s[ni][r] - mnew);
          s[ni][r] = p;
          rs += p;
        }
#pragma unroll
        for (int off = 8; off >= 1; off >>= 1)
          rs += __shfl_xor(rs, off);
        l_[r] = l_[r] * corr + rs;
#pragma unroll
        for (int nd = 0; nd < 4; ++nd) o[nd][r] *= corr;
      }

      // P -> LDS (wave-private rows)
#pragma unroll
      for (int ni = 0; ni < 8; ++ni)
#pragma unroll
        for (int r = 0; r < 4; ++r)
          Ps[wm + g * 4 + r][ni * 16 + lr] = (bf16)s[ni][r];

      // O += P @ V
      __builtin_amdgcn_s_setprio(1);
#pragma unroll
      for (int kk = 0; kk < 4; ++kk) {
        bf16x8 pf = *reinterpret_cast<const bf16x8*>(&Ps[wm + lr][kk * 32 + g * 8]);
#pragma unroll
        for (int nd = 0; nd < 4; ++nd) {
          bf16x8 vf = *reinterpret_cast<const bf16x8*>(&Vs[nd * 16 + lr][kk * 32 + g * 8]);
          o[nd] = mfma16(pf, vf, o[nd]);
        }
      }
      __builtin_amdgcn_s_setprio(0);
    }

    // epilogue for this phase
#pragma unroll
    for (int r = 0; r < 4; ++r) {
      int trow = q0 + wm + g * 4 + r;
      float inv = 1.0f / l_[r];
#pragma unroll
      for (int nd = 0; nd < 4; ++nd)
        O[((size_t)(b * T_SEQ + trow)) * DM + h * HD + nd * 16 + lr] = (bf16)(o[nd][r] * inv);
    }
  }
}

extern "C" void kernel_launch(void* const* d_in, const int* in_sizes, int n_in,
                              void* d_out, int out_size, void* d_ws, size_t ws_size,
                              hipStream_t stream) {
  const float* x      = (const float*)d_in[0];  // [8,1024,1024]
  const float* w_qkv  = (const float*)d_in[1];  // [3072,1024]
  const float* b_qkv  = (const float*)d_in[2];  // [3072]
  const float* w_proj = (const float*)d_in[3];  // [1024,1024]
  const float* b_proj = (const float*)d_in[4];  // [1024]
  const float* pos_in = (const float*)d_in[5];  // [256,2]
  float* out = (float*)d_out;

  char* ws = (char*)d_ws;
  bf16* xb     = (bf16*)(ws);                         // 16,777,216 B (reused as Ob)
  bf16* wqkvb  = (bf16*)(ws + 16777216);              //  6,291,456 B
  bf16* wprojb = (bf16*)(ws + 23068672);              //  2,097,152 B
  bf16* Qb     = (bf16*)(ws + 25165824);              // 16,777,216 B
  bf16* Kb     = (bf16*)(ws + 41943040);              // 16,777,216 B
  bf16* Vtb    = (bf16*)(ws + 58720256);              // 16,777,216 B
  float* table = (float*)(ws + 75497472);             //     65,536 B
  bf16* Ob = xb;  // attention output reuses xb (dead after gemm_qkv)

  const int nx = 8 * T_SEQ * DM, nwq = 3 * DM * DM, nwp = DM * DM;
  hope_bias_kernel<<<64, 256, 0, stream>>>(pos_in, table);
  cvt3_kernel<<<(nx + nwq + nwp) / 1024, 256, 0, stream>>>(
      x, xb, nx, w_qkv, wqkvb, nwq, w_proj, wprojb, nwp);

  gemm_qkv_kernel<<<1536, 256, 0, stream>>>(xb, wqkvb, b_qkv, Qb, Kb, Vtb);
  attn_kernel<<<dim3(4, 128), 512, 0, stream>>>(Qb, Kb, Vtb, table, Ob);
  gemm_proj_kernel<<<512, 256, 0, stream>>>(Ob, wprojb, b_proj, out);
}

// Round 5
// 205.499 us; speedup vs baseline: 2.0209x; 1.0272x over previous
//
#include <hip/hip_runtime.h>
#include <hip/hip_bf16.h>
#include <math.h>

typedef __bf16 bf16;
typedef __bf16 bf16x8 __attribute__((ext_vector_type(8)));
typedef __bf16 bf16x4 __attribute__((ext_vector_type(4)));
typedef float f32x4 __attribute__((ext_vector_type(4)));

#define T_SEQ 1024
#define NH 16
#define HD 64
#define DM 1024

__device__ __forceinline__ f32x4 mfma16(bf16x8 a, bf16x8 b, f32x4 c) {
  return __builtin_amdgcn_mfma_f32_16x16x32_bf16(a, b, c, 0, 0, 0);
}

__device__ __forceinline__ void gl_lds16(const bf16* g, bf16* l) {
  __builtin_amdgcn_global_load_lds(
      (const __attribute__((address_space(1))) void*)(g),
      (__attribute__((address_space(3))) void*)(l), 16, 0, 0);
}

// ---------------- bias table: table[h][d], d = i-j in [0,1023] ----------------
__global__ void hope_bias_kernel(const float* __restrict__ pi, float* __restrict__ table) {
  int idx = blockIdx.x * blockDim.x + threadIdx.x;
  if (idx >= 1024 * NH) return;
  int h = idx >> 10, d = idx & 1023;
  float s = 0.f;
  if (h < 8) {
    int p0 = h * 32;
    for (int t = 0; t < 32; ++t) {
      float f = expf(-(float)(p0 + t) * (9.210340371976184f / 512.0f));
      float theta = (float)d * f;
      s += cosf(theta) + sinf(theta);
    }
  } else {
    int p0 = (h - 8) * 32;
    for (int t = 0; t < 32; ++t)
      s += pi[(p0 + t) * 2] + pi[(p0 + t) * 2 + 1];
  }
  table[h * 1024 + d] = s;
}

// ---------------- merged f32 -> bf16 convert ----------------
__global__ void cvt3_kernel(const float* __restrict__ a, bf16* __restrict__ oa, int na,
                            const float* __restrict__ b, bf16* __restrict__ ob, int nb,
                            const float* __restrict__ c, bf16* __restrict__ oc, int nc) {
  int i = (blockIdx.x * blockDim.x + threadIdx.x) * 4;
  const float* src; bf16* dst; int off;
  if (i < na) { src = a; dst = oa; off = i; }
  else if (i < na + nb) { src = b; dst = ob; off = i - na; }
  else if (i < na + nb + nc) { src = c; dst = oc; off = i - na - nb; }
  else return;
  float4 v = *reinterpret_cast<const float4*>(src + off);
  bf16x4 o;
  o[0] = (bf16)v.x; o[1] = (bf16)v.y; o[2] = (bf16)v.z; o[3] = (bf16)v.w;
  *reinterpret_cast<bf16x4*>(dst + off) = o;
}

// ================= 8-phase 256x256 GEMM mainloop (K=1024, B^T inputs) =================
// LDS layout (bf16 elems): SA0[0..16383] SA1[16384..] SB0[32768..] SB1[49152..]
// Tile buffers: A[256][64], B[256][64]; read-swizzle: col ^= (row&7)<<3.
// Staging event EV (16KB): 0=Bh0(rows 0-127), 1=Ah0, 2=Ah1(128-255), 3=Bh1.
// During tile kt, phase P stages event P of tile kt+1 into the other buffer.
// Counted vmcnt(4) at end of each phase guarantees next phase's halves landed.

template<int EV>
__device__ __forceinline__ void stage_ev(const bf16* __restrict__ A, const bf16* __restrict__ Bt,
                                         int m0, int n0, int kt1,
                                         bf16* SAn, bf16* SBn, int tid) {
  const bf16* G = (EV == 1 || EV == 2) ? A : Bt;
  bf16* D = (EV == 1) ? SAn : (EV == 2) ? (SAn + 128 * 64)
          : (EV == 0) ? SBn : (SBn + 128 * 64);
  const int gr0 = ((EV == 1 || EV == 2) ? m0 : n0) + ((EV == 2 || EV == 3) ? 128 : 0);
  const int k0 = kt1 * 64;
#pragma unroll
  for (int c = 0; c < 2; ++c) {
    const int idx = c * 512 + tid;
    const int row = idx >> 3, cg = idx & 7;
    const int scg = cg ^ (row & 7);   // inverse-swizzled global source (linear LDS dest)
    const bf16* gp = &G[(size_t)(gr0 + row) * 1024 + k0 + scg * 8];
    bf16* lp = D + (size_t)(c * 512 + (tid & 448)) * 8;  // wave-uniform base
    gl_lds16(gp, lp);
  }
}

template<int P, int QM, int QN>
__device__ __forceinline__ void phase8(
    const bf16* SA, const bf16* SB, bf16* SAn, bf16* SBn,
    const bf16* __restrict__ A, const bf16* __restrict__ Bt,
    int m0, int n0, int kt1, f32x4 (&acc)[8][4],
    int tid, int wr, int wc, int g, int lr) {
  bf16x8 aF[4][2], bF[2][2];
  const int sw = (lr & 7) << 3;
#pragma unroll
  for (int j = 0; j < 4; ++j) {
    const int arow = (QM * 4 + j) * 32 + wr * 16 + lr;
#pragma unroll
    for (int kk = 0; kk < 2; ++kk)
      aF[j][kk] = *reinterpret_cast<const bf16x8*>(&SA[arow * 64 + ((kk * 32 + g * 8) ^ sw)]);
  }
#pragma unroll
  for (int j = 0; j < 2; ++j) {
    const int brow = (QN * 2 + j) * 64 + wc * 16 + lr;
#pragma unroll
    for (int kk = 0; kk < 2; ++kk)
      bF[j][kk] = *reinterpret_cast<const bf16x8*>(&SB[brow * 64 + ((kk * 32 + g * 8) ^ sw)]);
  }
  if (kt1 < 16) stage_ev<P>(A, Bt, m0, n0, kt1, SAn, SBn, tid);
  __builtin_amdgcn_s_barrier();
  __builtin_amdgcn_s_setprio(1);
#pragma unroll
  for (int j = 0; j < 4; ++j)
#pragma unroll
    for (int i = 0; i < 2; ++i)
#pragma unroll
      for (int kk = 0; kk < 2; ++kk)
        acc[QM * 4 + j][QN * 2 + i] = mfma16(aF[j][kk], bF[i][kk], acc[QM * 4 + j][QN * 2 + i]);
  __builtin_amdgcn_s_setprio(0);
  asm volatile("s_waitcnt vmcnt(4)" ::: "memory");
  __builtin_amdgcn_s_barrier();
}

template<int BUF>
__device__ __forceinline__ void ktile8(
    bf16* S, const bf16* __restrict__ A, const bf16* __restrict__ Bt,
    int m0, int n0, int kt, f32x4 (&acc)[8][4],
    int tid, int wr, int wc, int g, int lr) {
  bf16* SA = S + BUF * 16384;
  bf16* SB = S + 32768 + BUF * 16384;
  bf16* SAn = S + (BUF ^ 1) * 16384;
  bf16* SBn = S + 32768 + (BUF ^ 1) * 16384;
  const int kt1 = kt + 1;
  phase8<0, 0, 0>(SA, SB, SAn, SBn, A, Bt, m0, n0, kt1, acc, tid, wr, wc, g, lr);
  phase8<1, 1, 0>(SA, SB, SAn, SBn, A, Bt, m0, n0, kt1, acc, tid, wr, wc, g, lr);
  phase8<2, 1, 1>(SA, SB, SAn, SBn, A, Bt, m0, n0, kt1, acc, tid, wr, wc, g, lr);
  phase8<3, 0, 1>(SA, SB, SAn, SBn, A, Bt, m0, n0, kt1, acc, tid, wr, wc, g, lr);
}

__device__ __forceinline__ void gemm256_mainloop(
    bf16* S, const bf16* __restrict__ A, const bf16* __restrict__ Bt,
    int m0, int n0, f32x4 (&acc)[8][4],
    int tid, int wr, int wc, int g, int lr) {
  // prologue: stage tile 0 into buf0, order [Bh0, Ah0, Ah1, Bh1]
  stage_ev<0>(A, Bt, m0, n0, 0, S, S + 32768, tid);
  stage_ev<1>(A, Bt, m0, n0, 0, S, S + 32768, tid);
  stage_ev<2>(A, Bt, m0, n0, 0, S, S + 32768, tid);
  stage_ev<3>(A, Bt, m0, n0, 0, S, S + 32768, tid);
  asm volatile("s_waitcnt vmcnt(4)" ::: "memory");
  __builtin_amdgcn_s_barrier();
#pragma unroll 1
  for (int kt2 = 0; kt2 < 8; ++kt2) {
    ktile8<0>(S, A, Bt, m0, n0, kt2 * 2, acc, tid, wr, wc, g, lr);
    ktile8<1>(S, A, Bt, m0, n0, kt2 * 2 + 1, acc, tid, wr, wc, g, lr);
  }
}

// ---------------- QKV projection (8-phase): qkv[m,n] -> Q/K/Vt ----------------
__global__ __launch_bounds__(512, 2) void gemm_qkv8_kernel(
    const bf16* __restrict__ xb, const bf16* __restrict__ wb,
    const float* __restrict__ bias,
    bf16* __restrict__ Q, bf16* __restrict__ K, bf16* __restrict__ Vt) {
  extern __shared__ bf16 S[];
  const int tid = threadIdx.x;
  const int lane = tid & 63, wave = tid >> 6;
  const int wr = wave >> 2, wc = wave & 3;
  const int g = lane >> 4, lr = lane & 15;
  const int wg = blockIdx.x;                 // 0..383, 384 = 8 XCD x 48
  const int L = (wg & 7) * 48 + (wg >> 3);
  const int n0 = (L % 12) * 256;
  const int m0 = (L / 12) * 256;

  f32x4 acc[8][4];
  f32x4 z = {0.f, 0.f, 0.f, 0.f};
#pragma unroll
  for (int i = 0; i < 8; ++i)
#pragma unroll
    for (int j = 0; j < 4; ++j) acc[i][j] = z;

  gemm256_mainloop(S, xb, wb, m0, n0, acc, tid, wr, wc, g, lr);

  const int c3 = n0 >> 10;        // 0=Q, 1=K, 2=V (uniform per block)
  const int bb = m0 >> 10;        // batch (uniform)
  const int hbase = (n0 & 1023) >> 6;
#pragma unroll
  for (int mi = 0; mi < 8; ++mi) {
    const int t0 = (m0 & 1023) + mi * 32 + wr * 16 + g * 4;
#pragma unroll
    for (int ni = 0; ni < 4; ++ni) {
      const int col = n0 + ni * 64 + wc * 16 + lr;
      const float bv = bias[col];
      const int hh = hbase + ni;
      const int dd = wc * 16 + lr;
      const size_t bhh = (size_t)(bb * NH + hh);
      if (c3 == 2) {
        bf16x4 pk;
#pragma unroll
        for (int r = 0; r < 4; ++r) pk[r] = (bf16)(acc[mi][ni][r] + bv);
        *reinterpret_cast<bf16x4*>(&Vt[(bhh * HD + dd) * T_SEQ + t0]) = pk;
      } else {
        bf16* dst = (c3 == 0) ? Q : K;
#pragma unroll
        for (int r = 0; r < 4; ++r)
          dst[(bhh * T_SEQ + t0 + r) * HD + dd] = (bf16)(acc[mi][ni][r] + bv);
      }
    }
  }
}

// ---------------- output projection (8-phase): out = Ob @ wprojT + b ----------------
__global__ __launch_bounds__(512, 2) void gemm_proj8_kernel(
    const bf16* __restrict__ Ob, const bf16* __restrict__ wb,
    const float* __restrict__ bias, float* __restrict__ out) {
  extern __shared__ bf16 S[];
  const int tid = threadIdx.x;
  const int lane = tid & 63, wave = tid >> 6;
  const int wr = wave >> 2, wc = wave & 3;
  const int g = lane >> 4, lr = lane & 15;
  const int wg = blockIdx.x;                 // 0..127, 128 = 8 x 16
  const int L = (wg & 7) * 16 + (wg >> 3);
  const int n0 = (L % 4) * 256;
  const int m0 = (L / 4) * 256;

  f32x4 acc[8][4];
  f32x4 z = {0.f, 0.f, 0.f, 0.f};
#pragma unroll
  for (int i = 0; i < 8; ++i)
#pragma unroll
    for (int j = 0; j < 4; ++j) acc[i][j] = z;

  gemm256_mainloop(S, Ob, wb, m0, n0, acc, tid, wr, wc, g, lr);

#pragma unroll
  for (int mi = 0; mi < 8; ++mi) {
    const int row = m0 + mi * 32 + wr * 16 + g * 4;
#pragma unroll
    for (int ni = 0; ni < 4; ++ni) {
      const int col = n0 + ni * 64 + wc * 16 + lr;
      const float bv = bias[col];
#pragma unroll
      for (int r = 0; r < 4; ++r)
        out[(size_t)(row + r) * DM + col] = acc[mi][ni][r] + bv;
    }
  }
}

// ---------------- causal flash attention with HoPE bias ----------------
__global__ __launch_bounds__(512) void attn_kernel(
    const bf16* __restrict__ Q, const bf16* __restrict__ K,
    const bf16* __restrict__ Vt, const float* __restrict__ table,
    bf16* __restrict__ O)
{
  __shared__ bf16 Ks[128][72];
  __shared__ bf16 Vs[64][136];
  __shared__ bf16 Ps[128][136];
  __shared__ float tbl[1024];

  const int tid = threadIdx.x;
  const int lane = tid & 63;
  const int wave = tid >> 6;      // 0..7
  const int wm = wave * 16;
  const int g = lane >> 4;        // 0..3
  const int lr = lane & 15;
  const int qp = blockIdx.x;      // 0..3
  const int bh = blockIdx.y;
  const int h = bh & 15;
  const int b = bh >> 4;

  const bf16* Qp = Q + (size_t)bh * (T_SEQ * HD);
  const bf16* Kp = K + (size_t)bh * (T_SEQ * HD);
  const bf16* Vp = Vt + (size_t)bh * (HD * T_SEQ);

  for (int i = tid; i < 1024; i += 512) tbl[i] = table[h * 1024 + i];

  const int srow = tid >> 3, scol = (tid & 7) * 8;     // K staging
  const int vrow = tid >> 4, vcol = (tid & 15) * 8;    // V staging
  f32x4 z = {0.f, 0.f, 0.f, 0.f};

  for (int ph = 0; ph < 2; ++ph) {
    const int qt = ph ? qp : (7 - qp);
    const int q0 = qt * 128;
    const int nkt = qt + 1;

    bf16x8 qf[2];
#pragma unroll
    for (int kk = 0; kk < 2; ++kk)
      qf[kk] = *reinterpret_cast<const bf16x8*>(&Qp[(size_t)(q0 + wm + lr) * HD + kk * 32 + g * 8]);

    f32x4 o[4];
    float m_[4], l_[4];
#pragma unroll
    for (int i = 0; i < 4; ++i) { o[i] = z; m_[i] = -INFINITY; l_[i] = 0.f; }

    bf16x8 kreg[2], vreg[2];
    kreg[0] = *reinterpret_cast<const bf16x8*>(&Kp[(size_t)(srow) * HD + scol]);
    kreg[1] = *reinterpret_cast<const bf16x8*>(&Kp[(size_t)(64 + srow) * HD + scol]);
    vreg[0] = *reinterpret_cast<const bf16x8*>(&Vp[(size_t)(vrow) * T_SEQ + vcol]);
    vreg[1] = *reinterpret_cast<const bf16x8*>(&Vp[(size_t)(vrow + 32) * T_SEQ + vcol]);

    for (int kt = 0; kt < nkt; ++kt) {
      __syncthreads();
      *reinterpret_cast<bf16x8*>(&Ks[srow][scol]) = kreg[0];
      *reinterpret_cast<bf16x8*>(&Ks[srow + 64][scol]) = kreg[1];
      *reinterpret_cast<bf16x8*>(&Vs[vrow][vcol]) = vreg[0];
      *reinterpret_cast<bf16x8*>(&Vs[vrow + 32][vcol]) = vreg[1];
      __syncthreads();
      if (kt + 1 < nkt) {
        const int kb = (kt + 1) * 128;
        kreg[0] = *reinterpret_cast<const bf16x8*>(&Kp[(size_t)(kb + srow) * HD + scol]);
        kreg[1] = *reinterpret_cast<const bf16x8*>(&Kp[(size_t)(kb + 64 + srow) * HD + scol]);
        vreg[0] = *reinterpret_cast<const bf16x8*>(&Vp[(size_t)(vrow) * T_SEQ + kb + vcol]);
        vreg[1] = *reinterpret_cast<const bf16x8*>(&Vp[(size_t)(vrow + 32) * T_SEQ + kb + vcol]);
      }

      // S = Q K^T
      f32x4 s[8];
#pragma unroll
      for (int ni = 0; ni < 8; ++ni) s[ni] = z;
      __builtin_amdgcn_s_setprio(1);
#pragma unroll
      for (int ni = 0; ni < 8; ++ni) {
        bf16x8 kf0 = *reinterpret_cast<const bf16x8*>(&Ks[ni * 16 + lr][g * 8]);
        bf16x8 kf1 = *reinterpret_cast<const bf16x8*>(&Ks[ni * 16 + lr][32 + g * 8]);
        s[ni] = mfma16(qf[0], kf0, s[ni]);
        s[ni] = mfma16(qf[1], kf1, s[ni]);
      }
      __builtin_amdgcn_s_setprio(0);

      const int ib = q0 + wm + g * 4;
      const int jb = kt * 128 + lr;
      const bool diag = (kt == qt);
      float pm[4] = {-INFINITY, -INFINITY, -INFINITY, -INFINITY};
#pragma unroll
      for (int ni = 0; ni < 8; ++ni) {
#pragma unroll
        for (int r = 0; r < 4; ++r) {
          int d = (ib + r) - (jb + ni * 16);
          int dc = d < 0 ? 0 : d;
          float v = s[ni][r] * 0.125f + tbl[dc];
          if (diag && d < 0) v = -INFINITY;
          s[ni][r] = v;
          pm[r] = fmaxf(pm[r], v);
        }
      }
#pragma unroll
      for (int r = 0; r < 4; ++r) {
#pragma unroll
        for (int off = 8; off >= 1; off >>= 1)
          pm[r] = fmaxf(pm[r], __shfl_xor(pm[r], off));
        float mnew = fmaxf(m_[r], pm[r]);
        float corr = __expf(m_[r] - mnew);
        m_[r] = mnew;
        float rs = 0.f;
#pragma unroll
        for (int ni = 0; ni < 8; ++ni) {
          float p = __expf(s[ni][r] - mnew);
          s[ni][r] = p;
          rs += p;
        }
#pragma unroll
        for (int off = 8; off >= 1; off >>= 1)
          rs += __shfl_xor(rs, off);
        l_[r] = l_[r] * corr + rs;
#pragma unroll
        for (int nd = 0; nd < 4; ++nd) o[nd][r] *= corr;
      }

#pragma unroll
      for (int ni = 0; ni < 8; ++ni)
#pragma unroll
        for (int r = 0; r < 4; ++r)
          Ps[wm + g * 4 + r][ni * 16 + lr] = (bf16)s[ni][r];

      __builtin_amdgcn_s_setprio(1);
#pragma unroll
      for (int kk = 0; kk < 4; ++kk) {
        bf16x8 pf = *reinterpret_cast<const bf16x8*>(&Ps[wm + lr][kk * 32 + g * 8]);
#pragma unroll
        for (int nd = 0; nd < 4; ++nd) {
          bf16x8 vf = *reinterpret_cast<const bf16x8*>(&Vs[nd * 16 + lr][kk * 32 + g * 8]);
          o[nd] = mfma16(pf, vf, o[nd]);
        }
      }
      __builtin_amdgcn_s_setprio(0);
    }

#pragma unroll
    for (int r = 0; r < 4; ++r) {
      int trow = q0 + wm + g * 4 + r;
      float inv = 1.0f / l_[r];
#pragma unroll
      for (int nd = 0; nd < 4; ++nd)
        O[((size_t)(b * T_SEQ + trow)) * DM + h * HD + nd * 16 + lr] = (bf16)(o[nd][r] * inv);
    }
  }
}

extern "C" void kernel_launch(void* const* d_in, const int* in_sizes, int n_in,
                              void* d_out, int out_size, void* d_ws, size_t ws_size,
                              hipStream_t stream) {
  const float* x      = (const float*)d_in[0];
  const float* w_qkv  = (const float*)d_in[1];
  const float* b_qkv  = (const float*)d_in[2];
  const float* w_proj = (const float*)d_in[3];
  const float* b_proj = (const float*)d_in[4];
  const float* pos_in = (const float*)d_in[5];
  float* out = (float*)d_out;

  char* ws = (char*)d_ws;
  bf16* xb     = (bf16*)(ws);                         // 16 MB (reused as Ob)
  bf16* wqkvb  = (bf16*)(ws + 16777216);              //  6 MB
  bf16* wprojb = (bf16*)(ws + 23068672);              //  2 MB
  bf16* Qb     = (bf16*)(ws + 25165824);              // 16 MB
  bf16* Kb     = (bf16*)(ws + 41943040);              // 16 MB
  bf16* Vtb    = (bf16*)(ws + 58720256);              // 16 MB
  float* table = (float*)(ws + 75497472);             // 64 KB
  bf16* Ob = xb;

  static bool attr_done = false;
  if (!attr_done) {
    hipFuncSetAttribute((const void*)gemm_qkv8_kernel,
                        hipFuncAttributeMaxDynamicSharedMemorySize, 131072);
    hipFuncSetAttribute((const void*)gemm_proj8_kernel,
                        hipFuncAttributeMaxDynamicSharedMemorySize, 131072);
    attr_done = true;
  }

  const int nx = 8 * T_SEQ * DM, nwq = 3 * DM * DM, nwp = DM * DM;
  hope_bias_kernel<<<64, 256, 0, stream>>>(pos_in, table);
  cvt3_kernel<<<(nx + nwq + nwp) / 1024, 256, 0, stream>>>(
      x, xb, nx, w_qkv, wqkvb, nwq, w_proj, wprojb, nwp);

  gemm_qkv8_kernel<<<384, 512, 131072, stream>>>(xb, wqkvb, b_qkv, Qb, Kb, Vtb);
  attn_kernel<<<dim3(4, 128), 512, 0, stream>>>(Qb, Kb, Vtb, table, Ob);
  gemm_proj8_kernel<<<128, 512, 131072, stream>>>(Ob, wprojb, b_proj, out);
}

// Round 6
// 184.263 us; speedup vs baseline: 2.2538x; 1.1152x over previous
//
#include <hip/hip_runtime.h>
#include <hip/hip_bf16.h>
#include <math.h>

typedef __bf16 bf16;
typedef __bf16 bf16x8 __attribute__((ext_vector_type(8)));
typedef __bf16 bf16x4 __attribute__((ext_vector_type(4)));
typedef float f32x4 __attribute__((ext_vector_type(4)));
typedef float f32x16 __attribute__((ext_vector_type(16)));

#define T_SEQ 1024
#define NH 16
#define HD 64
#define DM 1024
#define LOG2E 1.44269504088896f

__device__ __forceinline__ f32x4 mfma16(bf16x8 a, bf16x8 b, f32x4 c) {
  return __builtin_amdgcn_mfma_f32_16x16x32_bf16(a, b, c, 0, 0, 0);
}
__device__ __forceinline__ f32x16 mfma32(bf16x8 a, bf16x8 b, f32x16 c) {
  return __builtin_amdgcn_mfma_f32_32x32x16_bf16(a, b, c, 0, 0, 0);
}

__device__ __forceinline__ void gl_lds16(const bf16* g, bf16* l) {
  __builtin_amdgcn_global_load_lds(
      (const __attribute__((address_space(1))) void*)(g),
      (__attribute__((address_space(3))) void*)(l), 16, 0, 0);
}

// ---------------- bias table: table[h][d] in exp2 (log2e-scaled) domain ----------------
__global__ void hope_bias_kernel(const float* __restrict__ pi, float* __restrict__ table) {
  int idx = blockIdx.x * blockDim.x + threadIdx.x;
  if (idx >= 1024 * NH) return;
  int h = idx >> 10, d = idx & 1023;
  float s = 0.f;
  if (h < 8) {
    int p0 = h * 32;
    for (int t = 0; t < 32; ++t) {
      float f = expf(-(float)(p0 + t) * (9.210340371976184f / 512.0f));
      float theta = (float)d * f;
      s += cosf(theta) + sinf(theta);
    }
  } else {
    int p0 = (h - 8) * 32;
    for (int t = 0; t < 32; ++t)
      s += pi[(p0 + t) * 2] + pi[(p0 + t) * 2 + 1];
  }
  table[h * 1024 + d] = s * LOG2E;
}

// ---------------- merged f32 -> bf16 convert ----------------
__global__ void cvt3_kernel(const float* __restrict__ a, bf16* __restrict__ oa, int na,
                            const float* __restrict__ b, bf16* __restrict__ ob, int nb,
                            const float* __restrict__ c, bf16* __restrict__ oc, int nc) {
  int i = (blockIdx.x * blockDim.x + threadIdx.x) * 4;
  const float* src; bf16* dst; int off;
  if (i < na) { src = a; dst = oa; off = i; }
  else if (i < na + nb) { src = b; dst = ob; off = i - na; }
  else if (i < na + nb + nc) { src = c; dst = oc; off = i - na - nb; }
  else return;
  float4 v = *reinterpret_cast<const float4*>(src + off);
  bf16x4 o;
  o[0] = (bf16)v.x; o[1] = (bf16)v.y; o[2] = (bf16)v.z; o[3] = (bf16)v.w;
  *reinterpret_cast<bf16x4*>(dst + off) = o;
}

// ================= 8-phase 256x256 GEMM mainloop (unchanged from R5) =================
template<int EV>
__device__ __forceinline__ void stage_ev(const bf16* __restrict__ A, const bf16* __restrict__ Bt,
                                         int m0, int n0, int kt1,
                                         bf16* SAn, bf16* SBn, int tid) {
  const bf16* G = (EV == 1 || EV == 2) ? A : Bt;
  bf16* D = (EV == 1) ? SAn : (EV == 2) ? (SAn + 128 * 64)
          : (EV == 0) ? SBn : (SBn + 128 * 64);
  const int gr0 = ((EV == 1 || EV == 2) ? m0 : n0) + ((EV == 2 || EV == 3) ? 128 : 0);
  const int k0 = kt1 * 64;
#pragma unroll
  for (int c = 0; c < 2; ++c) {
    const int idx = c * 512 + tid;
    const int row = idx >> 3, cg = idx & 7;
    const int scg = cg ^ (row & 7);
    const bf16* gp = &G[(size_t)(gr0 + row) * 1024 + k0 + scg * 8];
    bf16* lp = D + (size_t)(c * 512 + (tid & 448)) * 8;
    gl_lds16(gp, lp);
  }
}

template<int P, int QM, int QN>
__device__ __forceinline__ void phase8(
    const bf16* SA, const bf16* SB, bf16* SAn, bf16* SBn,
    const bf16* __restrict__ A, const bf16* __restrict__ Bt,
    int m0, int n0, int kt1, f32x4 (&acc)[8][4],
    int tid, int wr, int wc, int g, int lr) {
  bf16x8 aF[4][2], bF[2][2];
  const int sw = (lr & 7) << 3;
#pragma unroll
  for (int j = 0; j < 4; ++j) {
    const int arow = (QM * 4 + j) * 32 + wr * 16 + lr;
#pragma unroll
    for (int kk = 0; kk < 2; ++kk)
      aF[j][kk] = *reinterpret_cast<const bf16x8*>(&SA[arow * 64 + ((kk * 32 + g * 8) ^ sw)]);
  }
#pragma unroll
  for (int j = 0; j < 2; ++j) {
    const int brow = (QN * 2 + j) * 64 + wc * 16 + lr;
#pragma unroll
    for (int kk = 0; kk < 2; ++kk)
      bF[j][kk] = *reinterpret_cast<const bf16x8*>(&SB[brow * 64 + ((kk * 32 + g * 8) ^ sw)]);
  }
  if (kt1 < 16) stage_ev<P>(A, Bt, m0, n0, kt1, SAn, SBn, tid);
  __builtin_amdgcn_s_barrier();
  __builtin_amdgcn_s_setprio(1);
#pragma unroll
  for (int j = 0; j < 4; ++j)
#pragma unroll
    for (int i = 0; i < 2; ++i)
#pragma unroll
      for (int kk = 0; kk < 2; ++kk)
        acc[QM * 4 + j][QN * 2 + i] = mfma16(aF[j][kk], bF[i][kk], acc[QM * 4 + j][QN * 2 + i]);
  __builtin_amdgcn_s_setprio(0);
  asm volatile("s_waitcnt vmcnt(4)" ::: "memory");
  __builtin_amdgcn_s_barrier();
}

template<int BUF>
__device__ __forceinline__ void ktile8(
    bf16* S, const bf16* __restrict__ A, const bf16* __restrict__ Bt,
    int m0, int n0, int kt, f32x4 (&acc)[8][4],
    int tid, int wr, int wc, int g, int lr) {
  bf16* SA = S + BUF * 16384;
  bf16* SB = S + 32768 + BUF * 16384;
  bf16* SAn = S + (BUF ^ 1) * 16384;
  bf16* SBn = S + 32768 + (BUF ^ 1) * 16384;
  const int kt1 = kt + 1;
  phase8<0, 0, 0>(SA, SB, SAn, SBn, A, Bt, m0, n0, kt1, acc, tid, wr, wc, g, lr);
  phase8<1, 1, 0>(SA, SB, SAn, SBn, A, Bt, m0, n0, kt1, acc, tid, wr, wc, g, lr);
  phase8<2, 1, 1>(SA, SB, SAn, SBn, A, Bt, m0, n0, kt1, acc, tid, wr, wc, g, lr);
  phase8<3, 0, 1>(SA, SB, SAn, SBn, A, Bt, m0, n0, kt1, acc, tid, wr, wc, g, lr);
}

__device__ __forceinline__ void gemm256_mainloop(
    bf16* S, const bf16* __restrict__ A, const bf16* __restrict__ Bt,
    int m0, int n0, f32x4 (&acc)[8][4],
    int tid, int wr, int wc, int g, int lr) {
  stage_ev<0>(A, Bt, m0, n0, 0, S, S + 32768, tid);
  stage_ev<1>(A, Bt, m0, n0, 0, S, S + 32768, tid);
  stage_ev<2>(A, Bt, m0, n0, 0, S, S + 32768, tid);
  stage_ev<3>(A, Bt, m0, n0, 0, S, S + 32768, tid);
  asm volatile("s_waitcnt vmcnt(4)" ::: "memory");
  __builtin_amdgcn_s_barrier();
#pragma unroll 1
  for (int kt2 = 0; kt2 < 8; ++kt2) {
    ktile8<0>(S, A, Bt, m0, n0, kt2 * 2, acc, tid, wr, wc, g, lr);
    ktile8<1>(S, A, Bt, m0, n0, kt2 * 2 + 1, acc, tid, wr, wc, g, lr);
  }
}

// ---------------- QKV projection (8-phase) ----------------
__global__ __launch_bounds__(512, 2) void gemm_qkv8_kernel(
    const bf16* __restrict__ xb, const bf16* __restrict__ wb,
    const float* __restrict__ bias,
    bf16* __restrict__ Q, bf16* __restrict__ K, bf16* __restrict__ Vt) {
  extern __shared__ bf16 S[];
  const int tid = threadIdx.x;
  const int lane = tid & 63, wave = tid >> 6;
  const int wr = wave >> 2, wc = wave & 3;
  const int g = lane >> 4, lr = lane & 15;
  const int wg = blockIdx.x;
  const int L = (wg & 7) * 48 + (wg >> 3);
  const int n0 = (L % 12) * 256;
  const int m0 = (L / 12) * 256;

  f32x4 acc[8][4];
  f32x4 z = {0.f, 0.f, 0.f, 0.f};
#pragma unroll
  for (int i = 0; i < 8; ++i)
#pragma unroll
    for (int j = 0; j < 4; ++j) acc[i][j] = z;

  gemm256_mainloop(S, xb, wb, m0, n0, acc, tid, wr, wc, g, lr);

  const int c3 = n0 >> 10;
  const int bb = m0 >> 10;
  const int hbase = (n0 & 1023) >> 6;
#pragma unroll
  for (int mi = 0; mi < 8; ++mi) {
    const int t0 = (m0 & 1023) + mi * 32 + wr * 16 + g * 4;
#pragma unroll
    for (int ni = 0; ni < 4; ++ni) {
      const int col = n0 + ni * 64 + wc * 16 + lr;
      const float bv = bias[col];
      const int hh = hbase + ni;
      const int dd = wc * 16 + lr;
      const size_t bhh = (size_t)(bb * NH + hh);
      if (c3 == 2) {
        bf16x4 pk;
#pragma unroll
        for (int r = 0; r < 4; ++r) pk[r] = (bf16)(acc[mi][ni][r] + bv);
        *reinterpret_cast<bf16x4*>(&Vt[(bhh * HD + dd) * T_SEQ + t0]) = pk;
      } else {
        bf16* dst = (c3 == 0) ? Q : K;
#pragma unroll
        for (int r = 0; r < 4; ++r)
          dst[(bhh * T_SEQ + t0 + r) * HD + dd] = (bf16)(acc[mi][ni][r] + bv);
      }
    }
  }
}

// ---------------- output projection (8-phase) ----------------
__global__ __launch_bounds__(512, 2) void gemm_proj8_kernel(
    const bf16* __restrict__ Ob, const bf16* __restrict__ wb,
    const float* __restrict__ bias, float* __restrict__ out) {
  extern __shared__ bf16 S[];
  const int tid = threadIdx.x;
  const int lane = tid & 63, wave = tid >> 6;
  const int wr = wave >> 2, wc = wave & 3;
  const int g = lane >> 4, lr = lane & 15;
  const int wg = blockIdx.x;
  const int L = (wg & 7) * 16 + (wg >> 3);
  const int n0 = (L % 4) * 256;
  const int m0 = (L / 4) * 256;

  f32x4 acc[8][4];
  f32x4 z = {0.f, 0.f, 0.f, 0.f};
#pragma unroll
  for (int i = 0; i < 8; ++i)
#pragma unroll
    for (int j = 0; j < 4; ++j) acc[i][j] = z;

  gemm256_mainloop(S, Ob, wb, m0, n0, acc, tid, wr, wc, g, lr);

#pragma unroll
  for (int mi = 0; mi < 8; ++mi) {
    const int row = m0 + mi * 32 + wr * 16 + g * 4;
#pragma unroll
    for (int ni = 0; ni < 4; ++ni) {
      const int col = n0 + ni * 64 + wc * 16 + lr;
      const float bv = bias[col];
#pragma unroll
      for (int r = 0; r < 4; ++r)
        out[(size_t)(row + r) * DM + col] = acc[mi][ni][r] + bv;
    }
  }
}

// ---------------- causal flash attention, swapped-operand 32x32 ----------------
// grid 1024 blocks x 256 thr (4 waves x 32 q-rows = 128-row q-tile).
// S^T = mfma32(K, Q): lane owns q-row (lane&31), kv at crow(r,hi)=(r&3)+8(r>>2)+4hi.
// Softmax in-lane + one shfl_xor(32). P -> PV B-frag via pack + one 2-dword swap.
// O^T = mfma32(Vt, P). K/V in XOR-swizzled LDS via global_load_lds, double-buffered.
__device__ __forceinline__ uint2 pk4f(float a, float b, float c, float d) {
  bf16x4 v; v[0] = (bf16)a; v[1] = (bf16)b; v[2] = (bf16)c; v[3] = (bf16)d;
  uint2 u; __builtin_memcpy(&u, &v, 8); return u;
}

__global__ __launch_bounds__(256) void attn_kernel(
    const bf16* __restrict__ Q, const bf16* __restrict__ K,
    const bf16* __restrict__ Vt, const float* __restrict__ table,
    bf16* __restrict__ O)
{
  __shared__ bf16 Ks[2][64 * 64];
  __shared__ bf16 Vs[2][64 * 64];

  const int tid = threadIdx.x;
  const int lane = tid & 63;
  const int wq = tid >> 6;        // 0..3
  const int ql = lane & 31;
  const int hi = lane >> 5;
  const int ch = lane & 7;

  const int w = blockIdx.x;
  const int xcd = w & 7, idx = w >> 3;
  const int bh = xcd * 16 + (idx & 15);
  const int qt = 7 - (idx >> 4);          // long q-tiles dispatch first
  const int h = bh & 15, b = bh >> 4;
  const int q0 = qt * 128;
  const int nkt = 2 * qt + 2;

  const bf16* Qp = Q + (size_t)bh * (T_SEQ * HD);
  const bf16* Kp = K + (size_t)bh * (T_SEQ * HD);
  const bf16* Vp = Vt + (size_t)bh * (HD * T_SEQ);
  const float* tb = table + h * 1024;

  const int qg = q0 + wq * 32 + ql;

  bf16x8 qf[4];
#pragma unroll
  for (int cs = 0; cs < 4; ++cs)
    qf[cs] = *reinterpret_cast<const bf16x8*>(&Qp[(size_t)qg * HD + cs * 16 + hi * 8]);

  f32x16 o0, o1;
#pragma unroll
  for (int r = 0; r < 16; ++r) { o0[r] = 0.f; o1[r] = 0.f; }
  float m_ = -1e30f, l_ = 0.f;

  const int srow = wq * 16;
  const int lrow = lane >> 3;   // 0..7 within 8-row slab

  auto stage = [&](int kt, int buf) {
#pragma unroll
    for (int i = 0; i < 2; ++i) {
      const int r0 = srow + i * 8;
      const int row = r0 + lrow;
      gl_lds16(&Kp[(size_t)(kt * 64 + row) * HD + 8 * (ch ^ (row & 7))],
               &Ks[buf][r0 * 64]);
      gl_lds16(&Vp[(size_t)row * T_SEQ + kt * 64 + 8 * (ch ^ (row & 7))],
               &Vs[buf][r0 * 64]);
    }
  };

  stage(0, 0);
  __syncthreads();

  for (int kt = 0; kt < nkt; ++kt) {
    const int buf = kt & 1;

    // bias gathers from global (L1-hot), issued before staging so staging stays in flight
    float bias0[16], bias1[16];
#pragma unroll
    for (int r = 0; r < 16; ++r) {
      const int kvl = kt * 64 + (r & 3) + 8 * (r >> 2) + 4 * hi;
      int d0 = qg - kvl;
      int d1 = d0 - 32;
      bias0[r] = tb[d0 < 0 ? 0 : d0];
      bias1[r] = tb[d1 < 0 ? 0 : d1];
    }

    if (kt + 1 < nkt) stage(kt + 1, buf ^ 1);

    // S^T = K @ Q^T over c=64 (4 slices)
    f32x16 st0, st1;
#pragma unroll
    for (int r = 0; r < 16; ++r) { st0[r] = 0.f; st1[r] = 0.f; }
    __builtin_amdgcn_s_setprio(1);
#pragma unroll
    for (int cs = 0; cs < 4; ++cs) {
      bf16x8 k0 = *reinterpret_cast<const bf16x8*>(&Ks[buf][ql * 64 + (((2 * cs + hi) ^ ch) * 8)]);
      bf16x8 k1 = *reinterpret_cast<const bf16x8*>(&Ks[buf][(32 + ql) * 64 + (((2 * cs + hi) ^ ch) * 8)]);
      st0 = mfma32(k0, qf[cs], st0);
      st1 = mfma32(k1, qf[cs], st1);
    }
    __builtin_amdgcn_s_setprio(0);

    // scale + bias + mask (exp2 domain)
    const float SCALE2 = 0.125f * LOG2E;
#pragma unroll
    for (int r = 0; r < 16; ++r) {
      const int kvl = kt * 64 + (r & 3) + 8 * (r >> 2) + 4 * hi;
      const int d0 = qg - kvl;
      const int d1 = d0 - 32;
      float v0 = (d0 >= 0) ? st0[r] * SCALE2 + bias0[r] : -1e30f;
      float v1 = (d1 >= 0) ? st1[r] * SCALE2 + bias1[r] : -1e30f;
      st0[r] = v0; st1[r] = v1;
    }
    // in-lane max tree + cross-half combine
    float t8[8];
#pragma unroll
    for (int j = 0; j < 8; ++j)
      t8[j] = fmaxf(fmaxf(st0[j], st0[j + 8]), fmaxf(st1[j], st1[j + 8]));
#pragma unroll
    for (int j = 0; j < 4; ++j) t8[j] = fmaxf(t8[j], t8[j + 4]);
    float pmax = fmaxf(fmaxf(t8[0], t8[1]), fmaxf(t8[2], t8[3]));
    pmax = fmaxf(pmax, __shfl_xor(pmax, 32));
    const float mnew = fmaxf(m_, pmax);
    const float corr = exp2f(m_ - mnew);
    m_ = mnew;
    float s0 = 0.f, s1 = 0.f;
#pragma unroll
    for (int r = 0; r < 16; ++r) {
      float e0 = exp2f(st0[r] - mnew); st0[r] = e0; s0 += e0;
      float e1 = exp2f(st1[r] - mnew); st1[r] = e1; s1 += e1;
    }
    float sum = s0 + s1;
    sum += __shfl_xor(sum, 32);
    l_ = l_ * corr + sum;
#pragma unroll
    for (int r = 0; r < 16; ++r) { o0[r] *= corr; o1[r] *= corr; }

    // P fragments: per 16-kv slice, pack own groups + swap one bf16x4 with lane^32
    auto mkfrag = [&](const f32x16& p, int u) -> bf16x8 {
      uint2 A = pk4f(p[8 * u + 0], p[8 * u + 1], p[8 * u + 2], p[8 * u + 3]);
      uint2 B = pk4f(p[8 * u + 4], p[8 * u + 5], p[8 * u + 6], p[8 * u + 7]);
      uint2 send; send.x = hi ? A.x : B.x; send.y = hi ? A.y : B.y;
      uint2 recv; recv.x = __shfl_xor(send.x, 32); recv.y = __shfl_xor(send.y, 32);
      uint4 wf;
      wf.x = hi ? recv.x : A.x;  wf.y = hi ? recv.y : A.y;
      wf.z = hi ? B.x : recv.x;  wf.w = hi ? B.y : recv.y;
      bf16x8 fr; __builtin_memcpy(&fr, &wf, 16); return fr;
    };
    bf16x8 f0 = mkfrag(st0, 0);
    bf16x8 f1 = mkfrag(st0, 1);
    bf16x8 f2 = mkfrag(st1, 0);
    bf16x8 f3 = mkfrag(st1, 1);

    // O^T += Vt @ P^T over kv=64 (4 slices)
    __builtin_amdgcn_s_setprio(1);
#pragma unroll
    for (int s = 0; s < 4; ++s) {
      bf16x8 vf0 = *reinterpret_cast<const bf16x8*>(&Vs[buf][ql * 64 + (((2 * s + hi) ^ ch) * 8)]);
      bf16x8 vf1 = *reinterpret_cast<const bf16x8*>(&Vs[buf][(32 + ql) * 64 + (((2 * s + hi) ^ ch) * 8)]);
      bf16x8 pf = (s == 0) ? f0 : (s == 1) ? f1 : (s == 2) ? f2 : f3;
      o0 = mfma32(vf0, pf, o0);
      o1 = mfma32(vf1, pf, o1);
    }
    __builtin_amdgcn_s_setprio(0);

    __syncthreads();  // drains staging vmcnt; all waves done reading buf
  }

  // epilogue: O[b][qg][h*64 + d], d = 8*(r>>2) + 4*hi + (r&3) (+32 for o1)
  const float inv = 1.0f / l_;
  const size_t base = ((size_t)(b * T_SEQ + qg)) * DM + h * HD;
#pragma unroll
  for (int r4 = 0; r4 < 4; ++r4) {
    bf16x4 p0, p1;
#pragma unroll
    for (int j = 0; j < 4; ++j) {
      p0[j] = (bf16)(o0[r4 * 4 + j] * inv);
      p1[j] = (bf16)(o1[r4 * 4 + j] * inv);
    }
    *reinterpret_cast<bf16x4*>(&O[base + 8 * r4 + 4 * hi]) = p0;
    *reinterpret_cast<bf16x4*>(&O[base + 32 + 8 * r4 + 4 * hi]) = p1;
  }
}

extern "C" void kernel_launch(void* const* d_in, const int* in_sizes, int n_in,
                              void* d_out, int out_size, void* d_ws, size_t ws_size,
                              hipStream_t stream) {
  const float* x      = (const float*)d_in[0];
  const float* w_qkv  = (const float*)d_in[1];
  const float* b_qkv  = (const float*)d_in[2];
  const float* w_proj = (const float*)d_in[3];
  const float* b_proj = (const float*)d_in[4];
  const float* pos_in = (const float*)d_in[5];
  float* out = (float*)d_out;

  char* ws = (char*)d_ws;
  bf16* xb     = (bf16*)(ws);                         // 16 MB (reused as Ob)
  bf16* wqkvb  = (bf16*)(ws + 16777216);              //  6 MB
  bf16* wprojb = (bf16*)(ws + 23068672);              //  2 MB
  bf16* Qb     = (bf16*)(ws + 25165824);              // 16 MB
  bf16* Kb     = (bf16*)(ws + 41943040);              // 16 MB
  bf16* Vtb    = (bf16*)(ws + 58720256);              // 16 MB
  float* table = (float*)(ws + 75497472);             // 64 KB
  bf16* Ob = xb;

  static bool attr_done = false;
  if (!attr_done) {
    hipFuncSetAttribute((const void*)gemm_qkv8_kernel,
                        hipFuncAttributeMaxDynamicSharedMemorySize, 131072);
    hipFuncSetAttribute((const void*)gemm_proj8_kernel,
                        hipFuncAttributeMaxDynamicSharedMemorySize, 131072);
    attr_done = true;
  }

  const int nx = 8 * T_SEQ * DM, nwq = 3 * DM * DM, nwp = DM * DM;
  hope_bias_kernel<<<64, 256, 0, stream>>>(pos_in, table);
  cvt3_kernel<<<(nx + nwq + nwp) / 1024, 256, 0, stream>>>(
      x, xb, nx, w_qkv, wqkvb, nwq, w_proj, wprojb, nwp);

  gemm_qkv8_kernel<<<384, 512, 131072, stream>>>(xb, wqkvb, b_qkv, Qb, Kb, Vtb);
  attn_kernel<<<1024, 256, 0, stream>>>(Qb, Kb, Vtb, table, Ob);
  gemm_proj8_kernel<<<128, 512, 131072, stream>>>(Ob, wprojb, b_proj, out);
}

// Round 7
// 182.916 us; speedup vs baseline: 2.2704x; 1.0074x over previous
//
#include <hip/hip_runtime.h>
#include <hip/hip_bf16.h>
#include <math.h>

typedef __bf16 bf16;
typedef __bf16 bf16x8 __attribute__((ext_vector_type(8)));
typedef __bf16 bf16x4 __attribute__((ext_vector_type(4)));
typedef float f32x4 __attribute__((ext_vector_type(4)));
typedef float f32x16 __attribute__((ext_vector_type(16)));

#define T_SEQ 1024
#define NH 16
#define HD 64
#define DM 1024
#define LOG2E 1.44269504088896f

__device__ __forceinline__ f32x4 mfma16(bf16x8 a, bf16x8 b, f32x4 c) {
  return __builtin_amdgcn_mfma_f32_16x16x32_bf16(a, b, c, 0, 0, 0);
}
__device__ __forceinline__ f32x16 mfma32(bf16x8 a, bf16x8 b, f32x16 c) {
  return __builtin_amdgcn_mfma_f32_32x32x16_bf16(a, b, c, 0, 0, 0);
}

__device__ __forceinline__ void gl_lds16(const bf16* g, bf16* l) {
  __builtin_amdgcn_global_load_lds(
      (const __attribute__((address_space(1))) void*)(g),
      (__attribute__((address_space(3))) void*)(l), 16, 0, 0);
}

// ---------------- bias table: table[h][d] in exp2 (log2e-scaled) domain ----------------
__global__ void hope_bias_kernel(const float* __restrict__ pi, float* __restrict__ table) {
  int idx = blockIdx.x * blockDim.x + threadIdx.x;
  if (idx >= 1024 * NH) return;
  int h = idx >> 10, d = idx & 1023;
  float s = 0.f;
  if (h < 8) {
    int p0 = h * 32;
    for (int t = 0; t < 32; ++t) {
      float f = expf(-(float)(p0 + t) * (9.210340371976184f / 512.0f));
      float theta = (float)d * f;
      s += cosf(theta) + sinf(theta);
    }
  } else {
    int p0 = (h - 8) * 32;
    for (int t = 0; t < 32; ++t)
      s += pi[(p0 + t) * 2] + pi[(p0 + t) * 2 + 1];
  }
  table[h * 1024 + d] = s * LOG2E;
}

// ---------------- merged f32 -> bf16 convert ----------------
__global__ void cvt3_kernel(const float* __restrict__ a, bf16* __restrict__ oa, int na,
                            const float* __restrict__ b, bf16* __restrict__ ob, int nb,
                            const float* __restrict__ c, bf16* __restrict__ oc, int nc) {
  int i = (blockIdx.x * blockDim.x + threadIdx.x) * 4;
  const float* src; bf16* dst; int off;
  if (i < na) { src = a; dst = oa; off = i; }
  else if (i < na + nb) { src = b; dst = ob; off = i - na; }
  else if (i < na + nb + nc) { src = c; dst = oc; off = i - na - nb; }
  else return;
  float4 v = *reinterpret_cast<const float4*>(src + off);
  bf16x4 o;
  o[0] = (bf16)v.x; o[1] = (bf16)v.y; o[2] = (bf16)v.z; o[3] = (bf16)v.w;
  *reinterpret_cast<bf16x4*>(dst + off) = o;
}

// ================= 8-phase 256x256 GEMM mainloop, m201-style waits =================
// LDS (bf16 elems): SA0=S, SA1=S+16384, SB0=S+32768, SB1=S+49152.
// Half-tile = 128 rows x 64 cols (16 KB), staged by one stage_h (2 gl_lds/thread).
// Read swizzle: col ^ ((row&7)<<3); staged with inverse-swizzled global source.

__device__ __forceinline__ void stage_h(const bf16* __restrict__ G, int gr0, int t,
                                        bf16* D, int tid) {
  const int k0 = t * 64;
#pragma unroll
  for (int c = 0; c < 2; ++c) {
    const int idx = c * 512 + tid;
    const int row = idx >> 3, cg = idx & 7;
    const int scg = cg ^ (row & 7);
    gl_lds16(&G[(size_t)(gr0 + row) * 1024 + k0 + scg * 8],
             D + (size_t)(c * 512 + (tid & 448)) * 8);
  }
}

template<int QM, int QN>
__device__ __forceinline__ void ph_frags(const bf16* SA, const bf16* SB,
    bf16x8 (&aF)[4][2], bf16x8 (&bF)[2][2], int wr, int wc, int g, int lr) {
  const int sw = (lr & 7) << 3;
#pragma unroll
  for (int j = 0; j < 4; ++j) {
    const int arow = (QM * 4 + j) * 32 + wr * 16 + lr;
#pragma unroll
    for (int kk = 0; kk < 2; ++kk)
      aF[j][kk] = *reinterpret_cast<const bf16x8*>(&SA[arow * 64 + ((kk * 32 + g * 8) ^ sw)]);
  }
#pragma unroll
  for (int j = 0; j < 2; ++j) {
    const int brow = (QN * 2 + j) * 64 + wc * 16 + lr;
#pragma unroll
    for (int kk = 0; kk < 2; ++kk)
      bF[j][kk] = *reinterpret_cast<const bf16x8*>(&SB[brow * 64 + ((kk * 32 + g * 8) ^ sw)]);
  }
}

template<int QM, int QN>
__device__ __forceinline__ void ph_mfma(const bf16x8 (&aF)[4][2], const bf16x8 (&bF)[2][2],
                                        f32x4 (&acc)[8][4]) {
  __builtin_amdgcn_s_setprio(1);
#pragma unroll
  for (int j = 0; j < 4; ++j)
#pragma unroll
    for (int i = 0; i < 2; ++i)
#pragma unroll
      for (int kk = 0; kk < 2; ++kk)
        acc[QM * 4 + j][QN * 2 + i] = mfma16(aF[j][kk], bF[i][kk], acc[QM * 4 + j][QN * 2 + i]);
  __builtin_amdgcn_s_setprio(0);
}

// One iter = 2 K-tiles (t0 in buf0, t0+1 in buf1), 8 phases.
// Staging in dead slots; vmcnt(4) only at ph4 and ph8 (ledger verified).
template<bool LAST>
__device__ __forceinline__ void gemm_iter(bf16* S, const bf16* __restrict__ A,
    const bf16* __restrict__ Bt, int m0, int n0, int t0,
    f32x4 (&acc)[8][4], int tid, int wr, int wc, int g, int lr) {
  bf16* SA0 = S;            bf16* SA1 = S + 16384;
  bf16* SB0 = S + 32768;    bf16* SB1 = S + 49152;
  bf16x8 aF[4][2]; bf16x8 bF[2][2];

  // ph1: buf0 (A0,B0); stage buf1.A0(t0+1), buf1.B1(t0+1)
  ph_frags<0,0>(SA0, SB0, aF, bF, wr, wc, g, lr);
  stage_h(A, m0, t0 + 1, SA1, tid);
  stage_h(Bt, n0 + 128, t0 + 1, SB1 + 8192, tid);
  __builtin_amdgcn_s_barrier();
  ph_mfma<0,0>(aF, bF, acc);
  __builtin_amdgcn_s_barrier();

  // ph2: buf0 (A1,B0)
  ph_frags<1,0>(SA0, SB0, aF, bF, wr, wc, g, lr);
  __builtin_amdgcn_s_barrier();
  ph_mfma<1,0>(aF, bF, acc);
  __builtin_amdgcn_s_barrier();

  // ph3: buf0 (A1,B1); stage buf0.B0(t0+2)
  ph_frags<1,1>(SA0, SB0, aF, bF, wr, wc, g, lr);
  if (!LAST) stage_h(Bt, n0, t0 + 2, SB0, tid);
  __builtin_amdgcn_s_barrier();
  ph_mfma<1,1>(aF, bF, acc);
  __builtin_amdgcn_s_barrier();

  // ph4: buf0 (A0,B1); stage buf0.A1(t0+2); WAIT
  ph_frags<0,1>(SA0, SB0, aF, bF, wr, wc, g, lr);
  if (!LAST) stage_h(A, m0 + 128, t0 + 2, SA0 + 8192, tid);
  __builtin_amdgcn_s_barrier();
  ph_mfma<0,1>(aF, bF, acc);
  if (LAST) asm volatile("s_waitcnt vmcnt(0)" ::: "memory");
  else      asm volatile("s_waitcnt vmcnt(4)" ::: "memory");
  __builtin_amdgcn_s_barrier();

  // ph5: buf1 (A0,B0); stage buf0.B1(t0+2)
  ph_frags<0,0>(SA1, SB1, aF, bF, wr, wc, g, lr);
  if (!LAST) stage_h(Bt, n0 + 128, t0 + 2, SB0 + 8192, tid);
  __builtin_amdgcn_s_barrier();
  ph_mfma<0,0>(aF, bF, acc);
  __builtin_amdgcn_s_barrier();

  // ph6: buf1 (A1,B0); stage buf0.A0(t0+2)
  ph_frags<1,0>(SA1, SB1, aF, bF, wr, wc, g, lr);
  if (!LAST) stage_h(A, m0, t0 + 2, SA0, tid);
  __builtin_amdgcn_s_barrier();
  ph_mfma<1,0>(aF, bF, acc);
  __builtin_amdgcn_s_barrier();

  // ph7: buf1 (A1,B1); stage buf1.B0(t0+3)
  ph_frags<1,1>(SA1, SB1, aF, bF, wr, wc, g, lr);
  if (!LAST) stage_h(Bt, n0, t0 + 3, SB1, tid);
  __builtin_amdgcn_s_barrier();
  ph_mfma<1,1>(aF, bF, acc);
  __builtin_amdgcn_s_barrier();

  // ph8: buf1 (A0,B1); stage buf1.A1(t0+3); WAIT
  ph_frags<0,1>(SA1, SB1, aF, bF, wr, wc, g, lr);
  if (!LAST) stage_h(A, m0 + 128, t0 + 3, SA1 + 8192, tid);
  __builtin_amdgcn_s_barrier();
  ph_mfma<0,1>(aF, bF, acc);
  asm volatile("s_waitcnt vmcnt(4)" ::: "memory");
  __builtin_amdgcn_s_barrier();
}

__device__ __forceinline__ void gemm256_mainloop(
    bf16* S, const bf16* __restrict__ A, const bf16* __restrict__ Bt,
    int m0, int n0, f32x4 (&acc)[8][4],
    int tid, int wr, int wc, int g, int lr) {
  // prologue: buf0 t0 {B0,A1,B1,A0}, buf1 t1 {B0,A1}; wait first 4 events
  stage_h(Bt, n0,       0, S + 32768, tid);
  stage_h(A,  m0 + 128, 0, S + 8192, tid);
  stage_h(Bt, n0 + 128, 0, S + 32768 + 8192, tid);
  stage_h(A,  m0,       0, S, tid);
  stage_h(Bt, n0,       1, S + 49152, tid);
  stage_h(A,  m0 + 128, 1, S + 16384 + 8192, tid);
  asm volatile("s_waitcnt vmcnt(4)" ::: "memory");
  __builtin_amdgcn_s_barrier();
#pragma unroll 1
  for (int i = 0; i < 7; ++i)
    gemm_iter<false>(S, A, Bt, m0, n0, 2 * i, acc, tid, wr, wc, g, lr);
  gemm_iter<true>(S, A, Bt, m0, n0, 14, acc, tid, wr, wc, g, lr);
}

// ---------------- QKV projection (8-phase) ----------------
__global__ __launch_bounds__(512, 2) void gemm_qkv8_kernel(
    const bf16* __restrict__ xb, const bf16* __restrict__ wb,
    const float* __restrict__ bias,
    bf16* __restrict__ Q, bf16* __restrict__ K, bf16* __restrict__ Vt) {
  extern __shared__ bf16 S[];
  const int tid = threadIdx.x;
  const int lane = tid & 63, wave = tid >> 6;
  const int wr = wave >> 2, wc = wave & 3;
  const int g = lane >> 4, lr = lane & 15;
  const int wg = blockIdx.x;
  const int L = (wg & 7) * 48 + (wg >> 3);
  const int n0 = (L % 12) * 256;
  const int m0 = (L / 12) * 256;

  f32x4 acc[8][4];
  f32x4 z = {0.f, 0.f, 0.f, 0.f};
#pragma unroll
  for (int i = 0; i < 8; ++i)
#pragma unroll
    for (int j = 0; j < 4; ++j) acc[i][j] = z;

  gemm256_mainloop(S, xb, wb, m0, n0, acc, tid, wr, wc, g, lr);

  const int c3 = n0 >> 10;
  const int bb = m0 >> 10;
  const int hbase = (n0 & 1023) >> 6;
#pragma unroll
  for (int mi = 0; mi < 8; ++mi) {
    const int t0 = (m0 & 1023) + mi * 32 + wr * 16 + g * 4;
#pragma unroll
    for (int ni = 0; ni < 4; ++ni) {
      const int col = n0 + ni * 64 + wc * 16 + lr;
      const float bv = bias[col];
      const int hh = hbase + ni;
      const int dd = wc * 16 + lr;
      const size_t bhh = (size_t)(bb * NH + hh);
      if (c3 == 2) {
        bf16x4 pk;
#pragma unroll
        for (int r = 0; r < 4; ++r) pk[r] = (bf16)(acc[mi][ni][r] + bv);
        *reinterpret_cast<bf16x4*>(&Vt[(bhh * HD + dd) * T_SEQ + t0]) = pk;
      } else {
        bf16* dst = (c3 == 0) ? Q : K;
#pragma unroll
        for (int r = 0; r < 4; ++r)
          dst[(bhh * T_SEQ + t0 + r) * HD + dd] = (bf16)(acc[mi][ni][r] + bv);
      }
    }
  }
}

// ---------------- output projection (8-phase) ----------------
__global__ __launch_bounds__(512, 2) void gemm_proj8_kernel(
    const bf16* __restrict__ Ob, const bf16* __restrict__ wb,
    const float* __restrict__ bias, float* __restrict__ out) {
  extern __shared__ bf16 S[];
  const int tid = threadIdx.x;
  const int lane = tid & 63, wave = tid >> 6;
  const int wr = wave >> 2, wc = wave & 3;
  const int g = lane >> 4, lr = lane & 15;
  const int wg = blockIdx.x;
  const int L = (wg & 7) * 16 + (wg >> 3);
  const int n0 = (L % 4) * 256;
  const int m0 = (L / 4) * 256;

  f32x4 acc[8][4];
  f32x4 z = {0.f, 0.f, 0.f, 0.f};
#pragma unroll
  for (int i = 0; i < 8; ++i)
#pragma unroll
    for (int j = 0; j < 4; ++j) acc[i][j] = z;

  gemm256_mainloop(S, Ob, wb, m0, n0, acc, tid, wr, wc, g, lr);

#pragma unroll
  for (int mi = 0; mi < 8; ++mi) {
    const int row = m0 + mi * 32 + wr * 16 + g * 4;
#pragma unroll
    for (int ni = 0; ni < 4; ++ni) {
      const int col = n0 + ni * 64 + wc * 16 + lr;
      const float bv = bias[col];
#pragma unroll
      for (int r = 0; r < 4; ++r)
        out[(size_t)(row + r) * DM + col] = acc[mi][ni][r] + bv;
    }
  }
}

// ---------------- causal flash attention, swapped-operand 32x32 (unchanged) ----------------
__device__ __forceinline__ uint2 pk4f(float a, float b, float c, float d) {
  bf16x4 v; v[0] = (bf16)a; v[1] = (bf16)b; v[2] = (bf16)c; v[3] = (bf16)d;
  uint2 u; __builtin_memcpy(&u, &v, 8); return u;
}

__global__ __launch_bounds__(256) void attn_kernel(
    const bf16* __restrict__ Q, const bf16* __restrict__ K,
    const bf16* __restrict__ Vt, const float* __restrict__ table,
    bf16* __restrict__ O)
{
  __shared__ bf16 Ks[2][64 * 64];
  __shared__ bf16 Vs[2][64 * 64];

  const int tid = threadIdx.x;
  const int lane = tid & 63;
  const int wq = tid >> 6;
  const int ql = lane & 31;
  const int hi = lane >> 5;
  const int ch = lane & 7;

  const int w = blockIdx.x;
  const int xcd = w & 7, idx = w >> 3;
  const int bh = xcd * 16 + (idx & 15);
  const int qt = 7 - (idx >> 4);
  const int h = bh & 15, b = bh >> 4;
  const int q0 = qt * 128;
  const int nkt = 2 * qt + 2;

  const bf16* Qp = Q + (size_t)bh * (T_SEQ * HD);
  const bf16* Kp = K + (size_t)bh * (T_SEQ * HD);
  const bf16* Vp = Vt + (size_t)bh * (HD * T_SEQ);
  const float* tb = table + h * 1024;

  const int qg = q0 + wq * 32 + ql;

  bf16x8 qf[4];
#pragma unroll
  for (int cs = 0; cs < 4; ++cs)
    qf[cs] = *reinterpret_cast<const bf16x8*>(&Qp[(size_t)qg * HD + cs * 16 + hi * 8]);

  f32x16 o0, o1;
#pragma unroll
  for (int r = 0; r < 16; ++r) { o0[r] = 0.f; o1[r] = 0.f; }
  float m_ = -1e30f, l_ = 0.f;

  const int srow = wq * 16;
  const int lrow = lane >> 3;

  auto stage = [&](int kt, int buf) {
#pragma unroll
    for (int i = 0; i < 2; ++i) {
      const int r0 = srow + i * 8;
      const int row = r0 + lrow;
      gl_lds16(&Kp[(size_t)(kt * 64 + row) * HD + 8 * (ch ^ (row & 7))],
               &Ks[buf][r0 * 64]);
      gl_lds16(&Vp[(size_t)row * T_SEQ + kt * 64 + 8 * (ch ^ (row & 7))],
               &Vs[buf][r0 * 64]);
    }
  };

  stage(0, 0);
  __syncthreads();

  for (int kt = 0; kt < nkt; ++kt) {
    const int buf = kt & 1;

    float bias0[16], bias1[16];
#pragma unroll
    for (int r = 0; r < 16; ++r) {
      const int kvl = kt * 64 + (r & 3) + 8 * (r >> 2) + 4 * hi;
      int d0 = qg - kvl;
      int d1 = d0 - 32;
      bias0[r] = tb[d0 < 0 ? 0 : d0];
      bias1[r] = tb[d1 < 0 ? 0 : d1];
    }

    if (kt + 1 < nkt) stage(kt + 1, buf ^ 1);

    f32x16 st0, st1;
#pragma unroll
    for (int r = 0; r < 16; ++r) { st0[r] = 0.f; st1[r] = 0.f; }
    __builtin_amdgcn_s_setprio(1);
#pragma unroll
    for (int cs = 0; cs < 4; ++cs) {
      bf16x8 k0 = *reinterpret_cast<const bf16x8*>(&Ks[buf][ql * 64 + (((2 * cs + hi) ^ ch) * 8)]);
      bf16x8 k1 = *reinterpret_cast<const bf16x8*>(&Ks[buf][(32 + ql) * 64 + (((2 * cs + hi) ^ ch) * 8)]);
      st0 = mfma32(k0, qf[cs], st0);
      st1 = mfma32(k1, qf[cs], st1);
    }
    __builtin_amdgcn_s_setprio(0);

    const float SCALE2 = 0.125f * LOG2E;
#pragma unroll
    for (int r = 0; r < 16; ++r) {
      const int kvl = kt * 64 + (r & 3) + 8 * (r >> 2) + 4 * hi;
      const int d0 = qg - kvl;
      const int d1 = d0 - 32;
      float v0 = (d0 >= 0) ? st0[r] * SCALE2 + bias0[r] : -1e30f;
      float v1 = (d1 >= 0) ? st1[r] * SCALE2 + bias1[r] : -1e30f;
      st0[r] = v0; st1[r] = v1;
    }
    float t8[8];
#pragma unroll
    for (int j = 0; j < 8; ++j)
      t8[j] = fmaxf(fmaxf(st0[j], st0[j + 8]), fmaxf(st1[j], st1[j + 8]));
#pragma unroll
    for (int j = 0; j < 4; ++j) t8[j] = fmaxf(t8[j], t8[j + 4]);
    float pmax = fmaxf(fmaxf(t8[0], t8[1]), fmaxf(t8[2], t8[3]));
    pmax = fmaxf(pmax, __shfl_xor(pmax, 32));
    const float mnew = fmaxf(m_, pmax);
    const float corr = exp2f(m_ - mnew);
    m_ = mnew;
    float s0 = 0.f, s1 = 0.f;
#pragma unroll
    for (int r = 0; r < 16; ++r) {
      float e0 = exp2f(st0[r] - mnew); st0[r] = e0; s0 += e0;
      float e1 = exp2f(st1[r] - mnew); st1[r] = e1; s1 += e1;
    }
    float sum = s0 + s1;
    sum += __shfl_xor(sum, 32);
    l_ = l_ * corr + sum;
#pragma unroll
    for (int r = 0; r < 16; ++r) { o0[r] *= corr; o1[r] *= corr; }

    auto mkfrag = [&](const f32x16& p, int u) -> bf16x8 {
      uint2 A = pk4f(p[8 * u + 0], p[8 * u + 1], p[8 * u + 2], p[8 * u + 3]);
      uint2 B = pk4f(p[8 * u + 4], p[8 * u + 5], p[8 * u + 6], p[8 * u + 7]);
      uint2 send; send.x = hi ? A.x : B.x; send.y = hi ? A.y : B.y;
      uint2 recv; recv.x = __shfl_xor(send.x, 32); recv.y = __shfl_xor(send.y, 32);
      uint4 wf;
      wf.x = hi ? recv.x : A.x;  wf.y = hi ? recv.y : A.y;
      wf.z = hi ? B.x : recv.x;  wf.w = hi ? B.y : recv.y;
      bf16x8 fr; __builtin_memcpy(&fr, &wf, 16); return fr;
    };
    bf16x8 f0 = mkfrag(st0, 0);
    bf16x8 f1 = mkfrag(st0, 1);
    bf16x8 f2 = mkfrag(st1, 0);
    bf16x8 f3 = mkfrag(st1, 1);

    __builtin_amdgcn_s_setprio(1);
#pragma unroll
    for (int s = 0; s < 4; ++s) {
      bf16x8 vf0 = *reinterpret_cast<const bf16x8*>(&Vs[buf][ql * 64 + (((2 * s + hi) ^ ch) * 8)]);
      bf16x8 vf1 = *reinterpret_cast<const bf16x8*>(&Vs[buf][(32 + ql) * 64 + (((2 * s + hi) ^ ch) * 8)]);
      bf16x8 pf = (s == 0) ? f0 : (s == 1) ? f1 : (s == 2) ? f2 : f3;
      o0 = mfma32(vf0, pf, o0);
      o1 = mfma32(vf1, pf, o1);
    }
    __builtin_amdgcn_s_setprio(0);

    __syncthreads();
  }

  const float inv = 1.0f / l_;
  const size_t base = ((size_t)(b * T_SEQ + qg)) * DM + h * HD;
#pragma unroll
  for (int r4 = 0; r4 < 4; ++r4) {
    bf16x4 p0, p1;
#pragma unroll
    for (int j = 0; j < 4; ++j) {
      p0[j] = (bf16)(o0[r4 * 4 + j] * inv);
      p1[j] = (bf16)(o1[r4 * 4 + j] * inv);
    }
    *reinterpret_cast<bf16x4*>(&O[base + 8 * r4 + 4 * hi]) = p0;
    *reinterpret_cast<bf16x4*>(&O[base + 32 + 8 * r4 + 4 * hi]) = p1;
  }
}

extern "C" void kernel_launch(void* const* d_in, const int* in_sizes, int n_in,
                              void* d_out, int out_size, void* d_ws, size_t ws_size,
                              hipStream_t stream) {
  const float* x      = (const float*)d_in[0];
  const float* w_qkv  = (const float*)d_in[1];
  const float* b_qkv  = (const float*)d_in[2];
  const float* w_proj = (const float*)d_in[3];
  const float* b_proj = (const float*)d_in[4];
  const float* pos_in = (const float*)d_in[5];
  float* out = (float*)d_out;

  char* ws = (char*)d_ws;
  bf16* xb     = (bf16*)(ws);                         // 16 MB (reused as Ob)
  bf16* wqkvb  = (bf16*)(ws + 16777216);              //  6 MB
  bf16* wprojb = (bf16*)(ws + 23068672);              //  2 MB
  bf16* Qb     = (bf16*)(ws + 25165824);              // 16 MB
  bf16* Kb     = (bf16*)(ws + 41943040);              // 16 MB
  bf16* Vtb    = (bf16*)(ws + 58720256);              // 16 MB
  float* table = (float*)(ws + 75497472);             // 64 KB
  bf16* Ob = xb;

  static bool attr_done = false;
  if (!attr_done) {
    hipFuncSetAttribute((const void*)gemm_qkv8_kernel,
                        hipFuncAttributeMaxDynamicSharedMemorySize, 131072);
    hipFuncSetAttribute((const void*)gemm_proj8_kernel,
                        hipFuncAttributeMaxDynamicSharedMemorySize, 131072);
    attr_done = true;
  }

  const int nx = 8 * T_SEQ * DM, nwq = 3 * DM * DM, nwp = DM * DM;
  hope_bias_kernel<<<64, 256, 0, stream>>>(pos_in, table);
  cvt3_kernel<<<(nx + nwq + nwp) / 1024, 256, 0, stream>>>(
      x, xb, nx, w_qkv, wqkvb, nwq, w_proj, wprojb, nwp);

  gemm_qkv8_kernel<<<384, 512, 131072, stream>>>(xb, wqkvb, b_qkv, Qb, Kb, Vtb);
  attn_kernel<<<1024, 256, 0, stream>>>(Qb, Kb, Vtb, table, Ob);
  gemm_proj8_kernel<<<128, 512, 131072, stream>>>(Ob, wprojb, b_proj, out);
}

// Round 8
// 167.487 us; speedup vs baseline: 2.4795x; 1.0921x over previous
//
#include <hip/hip_runtime.h>
#include <hip/hip_bf16.h>
#include <math.h>

typedef __bf16 bf16;
typedef __bf16 bf16x8 __attribute__((ext_vector_type(8)));
typedef __bf16 bf16x4 __attribute__((ext_vector_type(4)));
typedef float f32x4 __attribute__((ext_vector_type(4)));
typedef float f32x16 __attribute__((ext_vector_type(16)));

#define T_SEQ 1024
#define NH 16
#define HD 64
#define DM 1024
#define LOG2E 1.44269504088896f

__device__ __forceinline__ f32x4 mfma16(bf16x8 a, bf16x8 b, f32x4 c) {
  return __builtin_amdgcn_mfma_f32_16x16x32_bf16(a, b, c, 0, 0, 0);
}
__device__ __forceinline__ f32x16 mfma32(bf16x8 a, bf16x8 b, f32x16 c) {
  return __builtin_amdgcn_mfma_f32_32x32x16_bf16(a, b, c, 0, 0, 0);
}

__device__ __forceinline__ void gl_lds16(const bf16* g, bf16* l) {
  __builtin_amdgcn_global_load_lds(
      (const __attribute__((address_space(1))) void*)(g),
      (__attribute__((address_space(3))) void*)(l), 16, 0, 0);
}

// ---------------- bias table: table[h][d] in exp2 (log2e-scaled) domain ----------------
__global__ void hope_bias_kernel(const float* __restrict__ pi, float* __restrict__ table) {
  int idx = blockIdx.x * blockDim.x + threadIdx.x;
  if (idx >= 1024 * NH) return;
  int h = idx >> 10, d = idx & 1023;
  float s = 0.f;
  if (h < 8) {
    int p0 = h * 32;
    for (int t = 0; t < 32; ++t) {
      float f = expf(-(float)(p0 + t) * (9.210340371976184f / 512.0f));
      float theta = (float)d * f;
      s += cosf(theta) + sinf(theta);
    }
  } else {
    int p0 = (h - 8) * 32;
    for (int t = 0; t < 32; ++t)
      s += pi[(p0 + t) * 2] + pi[(p0 + t) * 2 + 1];
  }
  table[h * 1024 + d] = s * LOG2E;
}

// ---------------- merged f32 -> bf16 convert ----------------
__global__ void cvt3_kernel(const float* __restrict__ a, bf16* __restrict__ oa, int na,
                            const float* __restrict__ b, bf16* __restrict__ ob, int nb,
                            const float* __restrict__ c, bf16* __restrict__ oc, int nc) {
  int i = (blockIdx.x * blockDim.x + threadIdx.x) * 4;
  const float* src; bf16* dst; int off;
  if (i < na) { src = a; dst = oa; off = i; }
  else if (i < na + nb) { src = b; dst = ob; off = i - na; }
  else if (i < na + nb + nc) { src = c; dst = oc; off = i - na - nb; }
  else return;
  float4 v = *reinterpret_cast<const float4*>(src + off);
  bf16x4 o;
  o[0] = (bf16)v.x; o[1] = (bf16)v.y; o[2] = (bf16)v.z; o[3] = (bf16)v.w;
  *reinterpret_cast<bf16x4*>(dst + off) = o;
}

// ================= 256x128 GEMM, BK=64, tri-buffered (K=1024, B^T inputs) =================
// Per buffer: A 256x64 (16384 elems) + B 128x64 (8192 elems) = 48 KB; 3 bufs = 144 KB.
// Read swizzle col ^ ((row&7)<<3); staged with inverse-swizzled global source.
// Per K-tile: 2 phases (A-half QM=0/1), each 16 MFMA + 12 ds_read_b128.
// Tile t+2 staged during tile t (3 x 16KB events = 6 loads); vmcnt(6) per K-tile.

__device__ __forceinline__ void stage_h(const bf16* __restrict__ G, int gr0, int t,
                                        bf16* D, int tid) {
  const int k0 = t * 64;
#pragma unroll
  for (int c = 0; c < 2; ++c) {
    const int idx = c * 512 + tid;
    const int row = idx >> 3, cg = idx & 7;
    const int scg = cg ^ (row & 7);
    gl_lds16(&G[(size_t)(gr0 + row) * 1024 + k0 + scg * 8],
             D + (size_t)(c * 512 + (tid & 448)) * 8);
  }
}

// One K-tile: buf BUF; optionally stage tile t2 into buf (BUF+2)%3.
// WAIT: 6 = steady (completes tile t+1's loads), 0 = drain, -1 = none.
template<int BUF, bool STG, int WAIT>
__device__ __forceinline__ void ktileN(bf16* S, const bf16* __restrict__ A,
    const bf16* __restrict__ Bt, int m0, int n0, int t2,
    f32x4 (&acc)[8][2], int tid, int wr, int wc, int g, int lr) {
  bf16* SA = S + BUF * 24576;
  bf16* SB = SA + 16384;
  bf16* SDn = S + ((BUF + 2) % 3) * 24576;
  const int sw = (lr & 7) << 3;
  bf16x8 aF[4][2], bF[2][2];

  // ---- phase 1: QM=0 ----
#pragma unroll
  for (int j = 0; j < 4; ++j)
#pragma unroll
    for (int kk = 0; kk < 2; ++kk)
      aF[j][kk] = *reinterpret_cast<const bf16x8*>(
          &SA[(j * 32 + wr * 16 + lr) * 64 + ((kk * 32 + g * 8) ^ sw)]);
#pragma unroll
  for (int j = 0; j < 2; ++j)
#pragma unroll
    for (int kk = 0; kk < 2; ++kk)
      bF[j][kk] = *reinterpret_cast<const bf16x8*>(
          &SB[(j * 64 + wc * 16 + lr) * 64 + ((kk * 32 + g * 8) ^ sw)]);
  if (STG) {
    stage_h(A, m0, t2, SDn, tid);              // A0 of t+2
    stage_h(Bt, n0, t2, SDn + 16384, tid);     // B  of t+2
  }
  __builtin_amdgcn_s_barrier();
  __builtin_amdgcn_s_setprio(1);
#pragma unroll
  for (int j = 0; j < 4; ++j)
#pragma unroll
    for (int i = 0; i < 2; ++i)
#pragma unroll
      for (int kk = 0; kk < 2; ++kk)
        acc[j][i] = mfma16(aF[j][kk], bF[i][kk], acc[j][i]);
  __builtin_amdgcn_s_setprio(0);
  __builtin_amdgcn_s_barrier();

  // ---- phase 2: QM=1 ----
#pragma unroll
  for (int j = 0; j < 4; ++j)
#pragma unroll
    for (int kk = 0; kk < 2; ++kk)
      aF[j][kk] = *reinterpret_cast<const bf16x8*>(
          &SA[((4 + j) * 32 + wr * 16 + lr) * 64 + ((kk * 32 + g * 8) ^ sw)]);
#pragma unroll
  for (int j = 0; j < 2; ++j)
#pragma unroll
    for (int kk = 0; kk < 2; ++kk)
      bF[j][kk] = *reinterpret_cast<const bf16x8*>(
          &SB[(j * 64 + wc * 16 + lr) * 64 + ((kk * 32 + g * 8) ^ sw)]);
  if (STG) stage_h(A, m0 + 128, t2, SDn + 8192, tid);   // A1 of t+2
  __builtin_amdgcn_s_barrier();
  __builtin_amdgcn_s_setprio(1);
#pragma unroll
  for (int j = 0; j < 4; ++j)
#pragma unroll
    for (int i = 0; i < 2; ++i)
#pragma unroll
      for (int kk = 0; kk < 2; ++kk)
        acc[4 + j][i] = mfma16(aF[j][kk], bF[i][kk], acc[4 + j][i]);
  __builtin_amdgcn_s_setprio(0);
  if (WAIT == 6)      asm volatile("s_waitcnt vmcnt(6)" ::: "memory");
  else if (WAIT == 0) asm volatile("s_waitcnt vmcnt(0)" ::: "memory");
  __builtin_amdgcn_s_barrier();
}

__device__ __forceinline__ void gemmN_mainloop(
    bf16* S, const bf16* __restrict__ A, const bf16* __restrict__ Bt,
    int m0, int n0, f32x4 (&acc)[8][2],
    int tid, int wr, int wc, int g, int lr) {
  // prologue: tiles 0 (buf0) and 1 (buf1)
  stage_h(A, m0, 0, S, tid);
  stage_h(Bt, n0, 0, S + 16384, tid);
  stage_h(A, m0 + 128, 0, S + 8192, tid);
  stage_h(A, m0, 1, S + 24576, tid);
  stage_h(Bt, n0, 1, S + 24576 + 16384, tid);
  stage_h(A, m0 + 128, 1, S + 24576 + 8192, tid);
  asm volatile("s_waitcnt vmcnt(6)" ::: "memory");
  __builtin_amdgcn_s_barrier();
  // 16 K-tiles; buf = kt%3; stage t+2 while kt<=13
  ktileN<0, true, 6>(S, A, Bt, m0, n0,  2, acc, tid, wr, wc, g, lr);
  ktileN<1, true, 6>(S, A, Bt, m0, n0,  3, acc, tid, wr, wc, g, lr);
  ktileN<2, true, 6>(S, A, Bt, m0, n0,  4, acc, tid, wr, wc, g, lr);
  ktileN<0, true, 6>(S, A, Bt, m0, n0,  5, acc, tid, wr, wc, g, lr);
  ktileN<1, true, 6>(S, A, Bt, m0, n0,  6, acc, tid, wr, wc, g, lr);
  ktileN<2, true, 6>(S, A, Bt, m0, n0,  7, acc, tid, wr, wc, g, lr);
  ktileN<0, true, 6>(S, A, Bt, m0, n0,  8, acc, tid, wr, wc, g, lr);
  ktileN<1, true, 6>(S, A, Bt, m0, n0,  9, acc, tid, wr, wc, g, lr);
  ktileN<2, true, 6>(S, A, Bt, m0, n0, 10, acc, tid, wr, wc, g, lr);
  ktileN<0, true, 6>(S, A, Bt, m0, n0, 11, acc, tid, wr, wc, g, lr);
  ktileN<1, true, 6>(S, A, Bt, m0, n0, 12, acc, tid, wr, wc, g, lr);
  ktileN<2, true, 6>(S, A, Bt, m0, n0, 13, acc, tid, wr, wc, g, lr);
  ktileN<0, true, 6>(S, A, Bt, m0, n0, 14, acc, tid, wr, wc, g, lr);
  ktileN<1, true, 6>(S, A, Bt, m0, n0, 15, acc, tid, wr, wc, g, lr);
  ktileN<2, false, 0>(S, A, Bt, m0, n0, 0, acc, tid, wr, wc, g, lr);
  ktileN<0, false, -1>(S, A, Bt, m0, n0, 0, acc, tid, wr, wc, g, lr);
}

// ---------------- QKV projection: grid 768 = 3 exact rounds ----------------
__global__ __launch_bounds__(512, 2) void gemm_qkv8_kernel(
    const bf16* __restrict__ xb, const bf16* __restrict__ wb,
    const float* __restrict__ bias,
    bf16* __restrict__ Q, bf16* __restrict__ K, bf16* __restrict__ Vt) {
  extern __shared__ bf16 S[];
  const int tid = threadIdx.x;
  const int lane = tid & 63, wave = tid >> 6;
  const int wr = wave >> 2, wc = wave & 3;
  const int g = lane >> 4, lr = lane & 15;
  const int wg = blockIdx.x;                  // 0..767; per-XCD 96 = 4m x 24n
  const int L = (wg & 7) * 96 + (wg >> 3);
  const int n0 = (L % 24) * 128;
  const int m0 = (L / 24) * 256;

  f32x4 acc[8][2];
  f32x4 z = {0.f, 0.f, 0.f, 0.f};
#pragma unroll
  for (int i = 0; i < 8; ++i) { acc[i][0] = z; acc[i][1] = z; }

  gemmN_mainloop(S, xb, wb, m0, n0, acc, tid, wr, wc, g, lr);

  const int c3 = n0 >> 10;        // 0=Q, 1=K, 2=V (uniform; 128-tile never straddles)
  const int bb = m0 >> 10;        // batch (uniform; 256-tile never straddles)
#pragma unroll
  for (int mi = 0; mi < 8; ++mi) {
    const int t0 = (m0 & 1023) + mi * 32 + wr * 16 + g * 4;
#pragma unroll
    for (int ni = 0; ni < 2; ++ni) {
      const int col = n0 + ni * 64 + wc * 16 + lr;
      const float bv = bias[col];
      const int hh = (col & 1023) >> 6;
      const int dd = col & 63;
      const size_t bhh = (size_t)(bb * NH + hh);
      if (c3 == 2) {
        bf16x4 pk;
#pragma unroll
        for (int r = 0; r < 4; ++r) pk[r] = (bf16)(acc[mi][ni][r] + bv);
        *reinterpret_cast<bf16x4*>(&Vt[(bhh * HD + dd) * T_SEQ + t0]) = pk;
      } else {
        bf16* dst = (c3 == 0) ? Q : K;
#pragma unroll
        for (int r = 0; r < 4; ++r)
          dst[(bhh * T_SEQ + t0 + r) * HD + dd] = (bf16)(acc[mi][ni][r] + bv);
      }
    }
  }
}

// ---------------- output projection: grid 256 = 1 exact round ----------------
__global__ __launch_bounds__(512, 2) void gemm_proj8_kernel(
    const bf16* __restrict__ Ob, const bf16* __restrict__ wb,
    const float* __restrict__ bias, float* __restrict__ out) {
  extern __shared__ bf16 S[];
  const int tid = threadIdx.x;
  const int lane = tid & 63, wave = tid >> 6;
  const int wr = wave >> 2, wc = wave & 3;
  const int g = lane >> 4, lr = lane & 15;
  const int wg = blockIdx.x;                  // 0..255; per-XCD 32 = 4m x 8n
  const int L = (wg & 7) * 32 + (wg >> 3);
  const int n0 = (L % 8) * 128;
  const int m0 = (L / 8) * 256;

  f32x4 acc[8][2];
  f32x4 z = {0.f, 0.f, 0.f, 0.f};
#pragma unroll
  for (int i = 0; i < 8; ++i) { acc[i][0] = z; acc[i][1] = z; }

  gemmN_mainloop(S, Ob, wb, m0, n0, acc, tid, wr, wc, g, lr);

#pragma unroll
  for (int mi = 0; mi < 8; ++mi) {
    const int row = m0 + mi * 32 + wr * 16 + g * 4;
#pragma unroll
    for (int ni = 0; ni < 2; ++ni) {
      const int col = n0 + ni * 64 + wc * 16 + lr;
      const float bv = bias[col];
#pragma unroll
      for (int r = 0; r < 4; ++r)
        out[(size_t)(row + r) * DM + col] = acc[mi][ni][r] + bv;
    }
  }
}

// ---------------- causal flash attention, swapped-operand 32x32 (unchanged) ----------------
__device__ __forceinline__ uint2 pk4f(float a, float b, float c, float d) {
  bf16x4 v; v[0] = (bf16)a; v[1] = (bf16)b; v[2] = (bf16)c; v[3] = (bf16)d;
  uint2 u; __builtin_memcpy(&u, &v, 8); return u;
}

__global__ __launch_bounds__(256) void attn_kernel(
    const bf16* __restrict__ Q, const bf16* __restrict__ K,
    const bf16* __restrict__ Vt, const float* __restrict__ table,
    bf16* __restrict__ O)
{
  __shared__ bf16 Ks[2][64 * 64];
  __shared__ bf16 Vs[2][64 * 64];

  const int tid = threadIdx.x;
  const int lane = tid & 63;
  const int wq = tid >> 6;
  const int ql = lane & 31;
  const int hi = lane >> 5;
  const int ch = lane & 7;

  const int w = blockIdx.x;
  const int xcd = w & 7, idx = w >> 3;
  const int bh = xcd * 16 + (idx & 15);
  const int qt = 7 - (idx >> 4);
  const int h = bh & 15, b = bh >> 4;
  const int q0 = qt * 128;
  const int nkt = 2 * qt + 2;

  const bf16* Qp = Q + (size_t)bh * (T_SEQ * HD);
  const bf16* Kp = K + (size_t)bh * (T_SEQ * HD);
  const bf16* Vp = Vt + (size_t)bh * (HD * T_SEQ);
  const float* tb = table + h * 1024;

  const int qg = q0 + wq * 32 + ql;

  bf16x8 qf[4];
#pragma unroll
  for (int cs = 0; cs < 4; ++cs)
    qf[cs] = *reinterpret_cast<const bf16x8*>(&Qp[(size_t)qg * HD + cs * 16 + hi * 8]);

  f32x16 o0, o1;
#pragma unroll
  for (int r = 0; r < 16; ++r) { o0[r] = 0.f; o1[r] = 0.f; }
  float m_ = -1e30f, l_ = 0.f;

  const int srow = wq * 16;
  const int lrow = lane >> 3;

  auto stage = [&](int kt, int buf) {
#pragma unroll
    for (int i = 0; i < 2; ++i) {
      const int r0 = srow + i * 8;
      const int row = r0 + lrow;
      gl_lds16(&Kp[(size_t)(kt * 64 + row) * HD + 8 * (ch ^ (row & 7))],
               &Ks[buf][r0 * 64]);
      gl_lds16(&Vp[(size_t)row * T_SEQ + kt * 64 + 8 * (ch ^ (row & 7))],
               &Vs[buf][r0 * 64]);
    }
  };

  stage(0, 0);
  __syncthreads();

  for (int kt = 0; kt < nkt; ++kt) {
    const int buf = kt & 1;

    float bias0[16], bias1[16];
#pragma unroll
    for (int r = 0; r < 16; ++r) {
      const int kvl = kt * 64 + (r & 3) + 8 * (r >> 2) + 4 * hi;
      int d0 = qg - kvl;
      int d1 = d0 - 32;
      bias0[r] = tb[d0 < 0 ? 0 : d0];
      bias1[r] = tb[d1 < 0 ? 0 : d1];
    }

    if (kt + 1 < nkt) stage(kt + 1, buf ^ 1);

    f32x16 st0, st1;
#pragma unroll
    for (int r = 0; r < 16; ++r) { st0[r] = 0.f; st1[r] = 0.f; }
    __builtin_amdgcn_s_setprio(1);
#pragma unroll
    for (int cs = 0; cs < 4; ++cs) {
      bf16x8 k0 = *reinterpret_cast<const bf16x8*>(&Ks[buf][ql * 64 + (((2 * cs + hi) ^ ch) * 8)]);
      bf16x8 k1 = *reinterpret_cast<const bf16x8*>(&Ks[buf][(32 + ql) * 64 + (((2 * cs + hi) ^ ch) * 8)]);
      st0 = mfma32(k0, qf[cs], st0);
      st1 = mfma32(k1, qf[cs], st1);
    }
    __builtin_amdgcn_s_setprio(0);

    const float SCALE2 = 0.125f * LOG2E;
#pragma unroll
    for (int r = 0; r < 16; ++r) {
      const int kvl = kt * 64 + (r & 3) + 8 * (r >> 2) + 4 * hi;
      const int d0 = qg - kvl;
      const int d1 = d0 - 32;
      float v0 = (d0 >= 0) ? st0[r] * SCALE2 + bias0[r] : -1e30f;
      float v1 = (d1 >= 0) ? st1[r] * SCALE2 + bias1[r] : -1e30f;
      st0[r] = v0; st1[r] = v1;
    }
    float t8[8];
#pragma unroll
    for (int j = 0; j < 8; ++j)
      t8[j] = fmaxf(fmaxf(st0[j], st0[j + 8]), fmaxf(st1[j], st1[j + 8]));
#pragma unroll
    for (int j = 0; j < 4; ++j) t8[j] = fmaxf(t8[j], t8[j + 4]);
    float pmax = fmaxf(fmaxf(t8[0], t8[1]), fmaxf(t8[2], t8[3]));
    pmax = fmaxf(pmax, __shfl_xor(pmax, 32));
    const float mnew = fmaxf(m_, pmax);
    const float corr = exp2f(m_ - mnew);
    m_ = mnew;
    float s0 = 0.f, s1 = 0.f;
#pragma unroll
    for (int r = 0; r < 16; ++r) {
      float e0 = exp2f(st0[r] - mnew); st0[r] = e0; s0 += e0;
      float e1 = exp2f(st1[r] - mnew); st1[r] = e1; s1 += e1;
    }
    float sum = s0 + s1;
    sum += __shfl_xor(sum, 32);
    l_ = l_ * corr + sum;
#pragma unroll
    for (int r = 0; r < 16; ++r) { o0[r] *= corr; o1[r] *= corr; }

    auto mkfrag = [&](const f32x16& p, int u) -> bf16x8 {
      uint2 A = pk4f(p[8 * u + 0], p[8 * u + 1], p[8 * u + 2], p[8 * u + 3]);
      uint2 B = pk4f(p[8 * u + 4], p[8 * u + 5], p[8 * u + 6], p[8 * u + 7]);
      uint2 send; send.x = hi ? A.x : B.x; send.y = hi ? A.y : B.y;
      uint2 recv; recv.x = __shfl_xor(send.x, 32); recv.y = __shfl_xor(send.y, 32);
      uint4 wf;
      wf.x = hi ? recv.x : A.x;  wf.y = hi ? recv.y : A.y;
      wf.z = hi ? B.x : recv.x;  wf.w = hi ? B.y : recv.y;
      bf16x8 fr; __builtin_memcpy(&fr, &wf, 16); return fr;
    };
    bf16x8 f0 = mkfrag(st0, 0);
    bf16x8 f1 = mkfrag(st0, 1);
    bf16x8 f2 = mkfrag(st1, 0);
    bf16x8 f3 = mkfrag(st1, 1);

    __builtin_amdgcn_s_setprio(1);
#pragma unroll
    for (int s = 0; s < 4; ++s) {
      bf16x8 vf0 = *reinterpret_cast<const bf16x8*>(&Vs[buf][ql * 64 + (((2 * s + hi) ^ ch) * 8)]);
      bf16x8 vf1 = *reinterpret_cast<const bf16x8*>(&Vs[buf][(32 + ql) * 64 + (((2 * s + hi) ^ ch) * 8)]);
      bf16x8 pf = (s == 0) ? f0 : (s == 1) ? f1 : (s == 2) ? f2 : f3;
      o0 = mfma32(vf0, pf, o0);
      o1 = mfma32(vf1, pf, o1);
    }
    __builtin_amdgcn_s_setprio(0);

    __syncthreads();
  }

  const float inv = 1.0f / l_;
  const size_t base = ((size_t)(b * T_SEQ + qg)) * DM + h * HD;
#pragma unroll
  for (int r4 = 0; r4 < 4; ++r4) {
    bf16x4 p0, p1;
#pragma unroll
    for (int j = 0; j < 4; ++j) {
      p0[j] = (bf16)(o0[r4 * 4 + j] * inv);
      p1[j] = (bf16)(o1[r4 * 4 + j] * inv);
    }
    *reinterpret_cast<bf16x4*>(&O[base + 8 * r4 + 4 * hi]) = p0;
    *reinterpret_cast<bf16x4*>(&O[base + 32 + 8 * r4 + 4 * hi]) = p1;
  }
}

extern "C" void kernel_launch(void* const* d_in, const int* in_sizes, int n_in,
                              void* d_out, int out_size, void* d_ws, size_t ws_size,
                              hipStream_t stream) {
  const float* x      = (const float*)d_in[0];
  const float* w_qkv  = (const float*)d_in[1];
  const float* b_qkv  = (const float*)d_in[2];
  const float* w_proj = (const float*)d_in[3];
  const float* b_proj = (const float*)d_in[4];
  const float* pos_in = (const float*)d_in[5];
  float* out = (float*)d_out;

  char* ws = (char*)d_ws;
  bf16* xb     = (bf16*)(ws);                         // 16 MB (reused as Ob)
  bf16* wqkvb  = (bf16*)(ws + 16777216);              //  6 MB
  bf16* wprojb = (bf16*)(ws + 23068672);              //  2 MB
  bf16* Qb     = (bf16*)(ws + 25165824);              // 16 MB
  bf16* Kb     = (bf16*)(ws + 41943040);              // 16 MB
  bf16* Vtb    = (bf16*)(ws + 58720256);              // 16 MB
  float* table = (float*)(ws + 75497472);             // 64 KB
  bf16* Ob = xb;

  static bool attr_done = false;
  if (!attr_done) {
    hipFuncSetAttribute((const void*)gemm_qkv8_kernel,
                        hipFuncAttributeMaxDynamicSharedMemorySize, 147456);
    hipFuncSetAttribute((const void*)gemm_proj8_kernel,
                        hipFuncAttributeMaxDynamicSharedMemorySize, 147456);
    attr_done = true;
  }

  const int nx = 8 * T_SEQ * DM, nwq = 3 * DM * DM, nwp = DM * DM;
  hope_bias_kernel<<<64, 256, 0, stream>>>(pos_in, table);
  cvt3_kernel<<<(nx + nwq + nwp) / 1024, 256, 0, stream>>>(
      x, xb, nx, w_qkv, wqkvb, nwq, w_proj, wprojb, nwp);

  gemm_qkv8_kernel<<<768, 512, 147456, stream>>>(xb, wqkvb, b_qkv, Qb, Kb, Vtb);
  attn_kernel<<<1024, 256, 0, stream>>>(Qb, Kb, Vtb, table, Ob);
  gemm_proj8_kernel<<<256, 512, 147456, stream>>>(Ob, wprojb, b_proj, out);
}

// Round 9
// 164.336 us; speedup vs baseline: 2.5271x; 1.0192x over previous
//
#include <hip/hip_runtime.h>
#include <hip/hip_bf16.h>
#include <math.h>

typedef __bf16 bf16;
typedef __bf16 bf16x8 __attribute__((ext_vector_type(8)));
typedef __bf16 bf16x4 __attribute__((ext_vector_type(4)));
typedef float f32x4 __attribute__((ext_vector_type(4)));
typedef float f32x16 __attribute__((ext_vector_type(16)));

#define T_SEQ 1024
#define NH 16
#define HD 64
#define DM 1024
#define LOG2E 1.44269504088896f

__device__ __forceinline__ f32x4 mfma16(bf16x8 a, bf16x8 b, f32x4 c) {
  return __builtin_amdgcn_mfma_f32_16x16x32_bf16(a, b, c, 0, 0, 0);
}
__device__ __forceinline__ f32x16 mfma32(bf16x8 a, bf16x8 b, f32x16 c) {
  return __builtin_amdgcn_mfma_f32_32x32x16_bf16(a, b, c, 0, 0, 0);
}

__device__ __forceinline__ void gl_lds16(const bf16* g, bf16* l) {
  __builtin_amdgcn_global_load_lds(
      (const __attribute__((address_space(1))) void*)(g),
      (__attribute__((address_space(3))) void*)(l), 16, 0, 0);
}

// ---------------- bias table: table[h][d] in exp2 (log2e-scaled) domain ----------------
__global__ void hope_bias_kernel(const float* __restrict__ pi, float* __restrict__ table) {
  int idx = blockIdx.x * blockDim.x + threadIdx.x;
  if (idx >= 1024 * NH) return;
  int h = idx >> 10, d = idx & 1023;
  float s = 0.f;
  if (h < 8) {
    int p0 = h * 32;
    for (int t = 0; t < 32; ++t) {
      float f = expf(-(float)(p0 + t) * (9.210340371976184f / 512.0f));
      float theta = (float)d * f;
      s += cosf(theta) + sinf(theta);
    }
  } else {
    int p0 = (h - 8) * 32;
    for (int t = 0; t < 32; ++t)
      s += pi[(p0 + t) * 2] + pi[(p0 + t) * 2 + 1];
  }
  table[h * 1024 + d] = s * LOG2E;
}

// ---------------- merged f32 -> bf16 convert ----------------
__global__ void cvt3_kernel(const float* __restrict__ a, bf16* __restrict__ oa, int na,
                            const float* __restrict__ b, bf16* __restrict__ ob, int nb,
                            const float* __restrict__ c, bf16* __restrict__ oc, int nc) {
  int i = (blockIdx.x * blockDim.x + threadIdx.x) * 4;
  const float* src; bf16* dst; int off;
  if (i < na) { src = a; dst = oa; off = i; }
  else if (i < na + nb) { src = b; dst = ob; off = i - na; }
  else if (i < na + nb + nc) { src = c; dst = oc; off = i - na - nb; }
  else return;
  float4 v = *reinterpret_cast<const float4*>(src + off);
  bf16x4 o;
  o[0] = (bf16)v.x; o[1] = (bf16)v.y; o[2] = (bf16)v.z; o[3] = (bf16)v.w;
  *reinterpret_cast<bf16x4*>(dst + off) = o;
}

// ================= 256x128 GEMM, BK=64, tri-buffered, 8 waves as 4x2 =================
// Wave-tile 64x64 (acc[4][4]); per K-tile 2 phases (kk halves): 8 ds_read_b128 + 16 MFMA each.
// Per buffer: A 256x64 + B 128x64 = 48 KB; 3 bufs = 144 KB.
// Read swizzle col ^ ((row&7)<<3); staged with inverse-swizzled global source.
// Tile t+2 staged during tile t (6 loads); vmcnt(6) per K-tile completes t+1.

__device__ __forceinline__ void stage_h(const bf16* __restrict__ G, int gr0, int t,
                                        bf16* D, int tid) {
  const int k0 = t * 64;
#pragma unroll
  for (int c = 0; c < 2; ++c) {
    const int idx = c * 512 + tid;
    const int row = idx >> 3, cg = idx & 7;
    const int scg = cg ^ (row & 7);
    gl_lds16(&G[(size_t)(gr0 + row) * 1024 + k0 + scg * 8],
             D + (size_t)(c * 512 + (tid & 448)) * 8);
  }
}

template<int BUF, bool STG, int WAIT>
__device__ __forceinline__ void ktileN(bf16* S, const bf16* __restrict__ A,
    const bf16* __restrict__ Bt, int m0, int n0, int t2,
    f32x4 (&acc)[4][4], int tid, int wr, int wc, int g, int lr) {
  bf16* SA = S + BUF * 24576;
  bf16* SB = SA + 16384;
  bf16* SDn = S + ((BUF + 2) % 3) * 24576;
  const int sw = (lr & 7) << 3;
  bf16x8 aF[4], bF[4];

  // ---- phase 1: kk=0 ----
#pragma unroll
  for (int j = 0; j < 4; ++j)
    aF[j] = *reinterpret_cast<const bf16x8*>(
        &SA[(wr * 64 + j * 16 + lr) * 64 + ((g * 8) ^ sw)]);
#pragma unroll
  for (int i = 0; i < 4; ++i)
    bF[i] = *reinterpret_cast<const bf16x8*>(
        &SB[(wc * 64 + i * 16 + lr) * 64 + ((g * 8) ^ sw)]);
  if (STG) {
    stage_h(A, m0, t2, SDn, tid);              // A0 of t+2
    stage_h(Bt, n0, t2, SDn + 16384, tid);     // B  of t+2
  }
  __builtin_amdgcn_s_barrier();
  __builtin_amdgcn_s_setprio(1);
#pragma unroll
  for (int j = 0; j < 4; ++j)
#pragma unroll
    for (int i = 0; i < 4; ++i)
      acc[j][i] = mfma16(aF[j], bF[i], acc[j][i]);
  __builtin_amdgcn_s_setprio(0);
  __builtin_amdgcn_s_barrier();

  // ---- phase 2: kk=1 ----
#pragma unroll
  for (int j = 0; j < 4; ++j)
    aF[j] = *reinterpret_cast<const bf16x8*>(
        &SA[(wr * 64 + j * 16 + lr) * 64 + ((32 + g * 8) ^ sw)]);
#pragma unroll
  for (int i = 0; i < 4; ++i)
    bF[i] = *reinterpret_cast<const bf16x8*>(
        &SB[(wc * 64 + i * 16 + lr) * 64 + ((32 + g * 8) ^ sw)]);
  if (STG) stage_h(A, m0 + 128, t2, SDn + 8192, tid);   // A1 of t+2
  __builtin_amdgcn_s_barrier();
  __builtin_amdgcn_s_setprio(1);
#pragma unroll
  for (int j = 0; j < 4; ++j)
#pragma unroll
    for (int i = 0; i < 4; ++i)
      acc[j][i] = mfma16(aF[j], bF[i], acc[j][i]);
  __builtin_amdgcn_s_setprio(0);
  if (WAIT == 6)      asm volatile("s_waitcnt vmcnt(6)" ::: "memory");
  else if (WAIT == 0) asm volatile("s_waitcnt vmcnt(0)" ::: "memory");
  __builtin_amdgcn_s_barrier();
}

__device__ __forceinline__ void gemmN_mainloop(
    bf16* S, const bf16* __restrict__ A, const bf16* __restrict__ Bt,
    int m0, int n0, f32x4 (&acc)[4][4],
    int tid, int wr, int wc, int g, int lr) {
  // prologue: tiles 0 (buf0) and 1 (buf1)
  stage_h(A, m0, 0, S, tid);
  stage_h(Bt, n0, 0, S + 16384, tid);
  stage_h(A, m0 + 128, 0, S + 8192, tid);
  stage_h(A, m0, 1, S + 24576, tid);
  stage_h(Bt, n0, 1, S + 24576 + 16384, tid);
  stage_h(A, m0 + 128, 1, S + 24576 + 8192, tid);
  asm volatile("s_waitcnt vmcnt(6)" ::: "memory");
  __builtin_amdgcn_s_barrier();
  // 16 K-tiles; buf = kt%3; stage t+2 while kt<=13
  ktileN<0, true, 6>(S, A, Bt, m0, n0,  2, acc, tid, wr, wc, g, lr);
  ktileN<1, true, 6>(S, A, Bt, m0, n0,  3, acc, tid, wr, wc, g, lr);
  ktileN<2, true, 6>(S, A, Bt, m0, n0,  4, acc, tid, wr, wc, g, lr);
  ktileN<0, true, 6>(S, A, Bt, m0, n0,  5, acc, tid, wr, wc, g, lr);
  ktileN<1, true, 6>(S, A, Bt, m0, n0,  6, acc, tid, wr, wc, g, lr);
  ktileN<2, true, 6>(S, A, Bt, m0, n0,  7, acc, tid, wr, wc, g, lr);
  ktileN<0, true, 6>(S, A, Bt, m0, n0,  8, acc, tid, wr, wc, g, lr);
  ktileN<1, true, 6>(S, A, Bt, m0, n0,  9, acc, tid, wr, wc, g, lr);
  ktileN<2, true, 6>(S, A, Bt, m0, n0, 10, acc, tid, wr, wc, g, lr);
  ktileN<0, true, 6>(S, A, Bt, m0, n0, 11, acc, tid, wr, wc, g, lr);
  ktileN<1, true, 6>(S, A, Bt, m0, n0, 12, acc, tid, wr, wc, g, lr);
  ktileN<2, true, 6>(S, A, Bt, m0, n0, 13, acc, tid, wr, wc, g, lr);
  ktileN<0, true, 6>(S, A, Bt, m0, n0, 14, acc, tid, wr, wc, g, lr);
  ktileN<1, true, 6>(S, A, Bt, m0, n0, 15, acc, tid, wr, wc, g, lr);
  ktileN<2, false, 0>(S, A, Bt, m0, n0, 0, acc, tid, wr, wc, g, lr);
  ktileN<0, false, -1>(S, A, Bt, m0, n0, 0, acc, tid, wr, wc, g, lr);
}

// ---------------- QKV projection: grid 768 = 3 exact rounds ----------------
// Per XCD: 4 m-tiles x 24 n-tiles, split into 2 super-cols of 12 n (B slice 3MB < L2).
__global__ __launch_bounds__(512, 2) void gemm_qkv8_kernel(
    const bf16* __restrict__ xb, const bf16* __restrict__ wb,
    const float* __restrict__ bias,
    bf16* __restrict__ Q, bf16* __restrict__ K, bf16* __restrict__ Vt) {
  extern __shared__ bf16 S[];
  const int tid = threadIdx.x;
  const int lane = tid & 63, wave = tid >> 6;
  const int wr = wave >> 1, wc = wave & 1;
  const int g = lane >> 4, lr = lane & 15;
  const int wg = blockIdx.x;                  // 0..767
  const int xcd = wg & 7, r = wg >> 3;        // r 0..95
  const int sc = r / 48, t = r % 48;          // super-col 0..1
  const int mi_ = t / 12, ni_ = sc * 12 + (t % 12);
  const int m0 = (xcd * 4 + mi_) * 256;
  const int n0 = ni_ * 128;

  f32x4 acc[4][4];
  f32x4 z = {0.f, 0.f, 0.f, 0.f};
#pragma unroll
  for (int i = 0; i < 4; ++i)
#pragma unroll
    for (int j = 0; j < 4; ++j) acc[i][j] = z;

  gemmN_mainloop(S, xb, wb, m0, n0, acc, tid, wr, wc, g, lr);

  const int c3 = n0 >> 10;        // 0=Q, 1=K, 2=V (uniform; 128-tile never straddles)
  const int bb = m0 >> 10;        // batch (uniform; 256-tile never straddles)
#pragma unroll
  for (int mi = 0; mi < 4; ++mi) {
    const int t0 = (m0 & 1023) + wr * 64 + mi * 16 + g * 4;
#pragma unroll
    for (int ni = 0; ni < 4; ++ni) {
      const int col = n0 + wc * 64 + ni * 16 + lr;
      const float bv = bias[col];
      const int hh = (col & 1023) >> 6;
      const int dd = col & 63;
      const size_t bhh = (size_t)(bb * NH + hh);
      if (c3 == 2) {
        bf16x4 pk;
#pragma unroll
        for (int r4 = 0; r4 < 4; ++r4) pk[r4] = (bf16)(acc[mi][ni][r4] + bv);
        *reinterpret_cast<bf16x4*>(&Vt[(bhh * HD + dd) * T_SEQ + t0]) = pk;
      } else {
        bf16* dst = (c3 == 0) ? Q : K;
#pragma unroll
        for (int r4 = 0; r4 < 4; ++r4)
          dst[(bhh * T_SEQ + t0 + r4) * HD + dd] = (bf16)(acc[mi][ni][r4] + bv);
      }
    }
  }
}

// ---------------- output projection: grid 256 = 1 exact round ----------------
__global__ __launch_bounds__(512, 2) void gemm_proj8_kernel(
    const bf16* __restrict__ Ob, const bf16* __restrict__ wb,
    const float* __restrict__ bias, float* __restrict__ out) {
  extern __shared__ bf16 S[];
  const int tid = threadIdx.x;
  const int lane = tid & 63, wave = tid >> 6;
  const int wr = wave >> 1, wc = wave & 1;
  const int g = lane >> 4, lr = lane & 15;
  const int wg = blockIdx.x;                  // 0..255; per-XCD 32 = 4m x 8n
  const int L = (wg & 7) * 32 + (wg >> 3);
  const int n0 = (L % 8) * 128;
  const int m0 = (L / 8) * 256;

  f32x4 acc[4][4];
  f32x4 z = {0.f, 0.f, 0.f, 0.f};
#pragma unroll
  for (int i = 0; i < 4; ++i)
#pragma unroll
    for (int j = 0; j < 4; ++j) acc[i][j] = z;

  gemmN_mainloop(S, Ob, wb, m0, n0, acc, tid, wr, wc, g, lr);

#pragma unroll
  for (int mi = 0; mi < 4; ++mi) {
    const int row = m0 + wr * 64 + mi * 16 + g * 4;
#pragma unroll
    for (int ni = 0; ni < 4; ++ni) {
      const int col = n0 + wc * 64 + ni * 16 + lr;
      const float bv = bias[col];
#pragma unroll
      for (int r4 = 0; r4 < 4; ++r4)
        out[(size_t)(row + r4) * DM + col] = acc[mi][ni][r4] + bv;
    }
  }
}

// ---------------- causal flash attention, swapped-operand 32x32 (unchanged) ----------------
__device__ __forceinline__ uint2 pk4f(float a, float b, float c, float d) {
  bf16x4 v; v[0] = (bf16)a; v[1] = (bf16)b; v[2] = (bf16)c; v[3] = (bf16)d;
  uint2 u; __builtin_memcpy(&u, &v, 8); return u;
}

__global__ __launch_bounds__(256) void attn_kernel(
    const bf16* __restrict__ Q, const bf16* __restrict__ K,
    const bf16* __restrict__ Vt, const float* __restrict__ table,
    bf16* __restrict__ O)
{
  __shared__ bf16 Ks[2][64 * 64];
  __shared__ bf16 Vs[2][64 * 64];

  const int tid = threadIdx.x;
  const int lane = tid & 63;
  const int wq = tid >> 6;
  const int ql = lane & 31;
  const int hi = lane >> 5;
  const int ch = lane & 7;

  const int w = blockIdx.x;
  const int xcd = w & 7, idx = w >> 3;
  const int bh = xcd * 16 + (idx & 15);
  const int qt = 7 - (idx >> 4);
  const int h = bh & 15, b = bh >> 4;
  const int q0 = qt * 128;
  const int nkt = 2 * qt + 2;

  const bf16* Qp = Q + (size_t)bh * (T_SEQ * HD);
  const bf16* Kp = K + (size_t)bh * (T_SEQ * HD);
  const bf16* Vp = Vt + (size_t)bh * (HD * T_SEQ);
  const float* tb = table + h * 1024;

  const int qg = q0 + wq * 32 + ql;

  bf16x8 qf[4];
#pragma unroll
  for (int cs = 0; cs < 4; ++cs)
    qf[cs] = *reinterpret_cast<const bf16x8*>(&Qp[(size_t)qg * HD + cs * 16 + hi * 8]);

  f32x16 o0, o1;
#pragma unroll
  for (int r = 0; r < 16; ++r) { o0[r] = 0.f; o1[r] = 0.f; }
  float m_ = -1e30f, l_ = 0.f;

  const int srow = wq * 16;
  const int lrow = lane >> 3;

  auto stage = [&](int kt, int buf) {
#pragma unroll
    for (int i = 0; i < 2; ++i) {
      const int r0 = srow + i * 8;
      const int row = r0 + lrow;
      gl_lds16(&Kp[(size_t)(kt * 64 + row) * HD + 8 * (ch ^ (row & 7))],
               &Ks[buf][r0 * 64]);
      gl_lds16(&Vp[(size_t)row * T_SEQ + kt * 64 + 8 * (ch ^ (row & 7))],
               &Vs[buf][r0 * 64]);
    }
  };

  stage(0, 0);
  __syncthreads();

  for (int kt = 0; kt < nkt; ++kt) {
    const int buf = kt & 1;

    float bias0[16], bias1[16];
#pragma unroll
    for (int r = 0; r < 16; ++r) {
      const int kvl = kt * 64 + (r & 3) + 8 * (r >> 2) + 4 * hi;
      int d0 = qg - kvl;
      int d1 = d0 - 32;
      bias0[r] = tb[d0 < 0 ? 0 : d0];
      bias1[r] = tb[d1 < 0 ? 0 : d1];
    }

    if (kt + 1 < nkt) stage(kt + 1, buf ^ 1);

    f32x16 st0, st1;
#pragma unroll
    for (int r = 0; r < 16; ++r) { st0[r] = 0.f; st1[r] = 0.f; }
    __builtin_amdgcn_s_setprio(1);
#pragma unroll
    for (int cs = 0; cs < 4; ++cs) {
      bf16x8 k0 = *reinterpret_cast<const bf16x8*>(&Ks[buf][ql * 64 + (((2 * cs + hi) ^ ch) * 8)]);
      bf16x8 k1 = *reinterpret_cast<const bf16x8*>(&Ks[buf][(32 + ql) * 64 + (((2 * cs + hi) ^ ch) * 8)]);
      st0 = mfma32(k0, qf[cs], st0);
      st1 = mfma32(k1, qf[cs], st1);
    }
    __builtin_amdgcn_s_setprio(0);

    const float SCALE2 = 0.125f * LOG2E;
#pragma unroll
    for (int r = 0; r < 16; ++r) {
      const int kvl = kt * 64 + (r & 3) + 8 * (r >> 2) + 4 * hi;
      const int d0 = qg - kvl;
      const int d1 = d0 - 32;
      float v0 = (d0 >= 0) ? st0[r] * SCALE2 + bias0[r] : -1e30f;
      float v1 = (d1 >= 0) ? st1[r] * SCALE2 + bias1[r] : -1e30f;
      st0[r] = v0; st1[r] = v1;
    }
    float t8[8];
#pragma unroll
    for (int j = 0; j < 8; ++j)
      t8[j] = fmaxf(fmaxf(st0[j], st0[j + 8]), fmaxf(st1[j], st1[j + 8]));
#pragma unroll
    for (int j = 0; j < 4; ++j) t8[j] = fmaxf(t8[j], t8[j + 4]);
    float pmax = fmaxf(fmaxf(t8[0], t8[1]), fmaxf(t8[2], t8[3]));
    pmax = fmaxf(pmax, __shfl_xor(pmax, 32));
    const float mnew = fmaxf(m_, pmax);
    const float corr = exp2f(m_ - mnew);
    m_ = mnew;
    float s0 = 0.f, s1 = 0.f;
#pragma unroll
    for (int r = 0; r < 16; ++r) {
      float e0 = exp2f(st0[r] - mnew); st0[r] = e0; s0 += e0;
      float e1 = exp2f(st1[r] - mnew); st1[r] = e1; s1 += e1;
    }
    float sum = s0 + s1;
    sum += __shfl_xor(sum, 32);
    l_ = l_ * corr + sum;
#pragma unroll
    for (int r = 0; r < 16; ++r) { o0[r] *= corr; o1[r] *= corr; }

    auto mkfrag = [&](const f32x16& p, int u) -> bf16x8 {
      uint2 A = pk4f(p[8 * u + 0], p[8 * u + 1], p[8 * u + 2], p[8 * u + 3]);
      uint2 B = pk4f(p[8 * u + 4], p[8 * u + 5], p[8 * u + 6], p[8 * u + 7]);
      uint2 send; send.x = hi ? A.x : B.x; send.y = hi ? A.y : B.y;
      uint2 recv; recv.x = __shfl_xor(send.x, 32); recv.y = __shfl_xor(send.y, 32);
      uint4 wf;
      wf.x = hi ? recv.x : A.x;  wf.y = hi ? recv.y : A.y;
      wf.z = hi ? B.x : recv.x;  wf.w = hi ? B.y : recv.y;
      bf16x8 fr; __builtin_memcpy(&fr, &wf, 16); return fr;
    };
    bf16x8 f0 = mkfrag(st0, 0);
    bf16x8 f1 = mkfrag(st0, 1);
    bf16x8 f2 = mkfrag(st1, 0);
    bf16x8 f3 = mkfrag(st1, 1);

    __builtin_amdgcn_s_setprio(1);
#pragma unroll
    for (int s = 0; s < 4; ++s) {
      bf16x8 vf0 = *reinterpret_cast<const bf16x8*>(&Vs[buf][ql * 64 + (((2 * s + hi) ^ ch) * 8)]);
      bf16x8 vf1 = *reinterpret_cast<const bf16x8*>(&Vs[buf][(32 + ql) * 64 + (((2 * s + hi) ^ ch) * 8)]);
      bf16x8 pf = (s == 0) ? f0 : (s == 1) ? f1 : (s == 2) ? f2 : f3;
      o0 = mfma32(vf0, pf, o0);
      o1 = mfma32(vf1, pf, o1);
    }
    __builtin_amdgcn_s_setprio(0);

    __syncthreads();
  }

  const float inv = 1.0f / l_;
  const size_t base = ((size_t)(b * T_SEQ + qg)) * DM + h * HD;
#pragma unroll
  for (int r4 = 0; r4 < 4; ++r4) {
    bf16x4 p0, p1;
#pragma unroll
    for (int j = 0; j < 4; ++j) {
      p0[j] = (bf16)(o0[r4 * 4 + j] * inv);
      p1[j] = (bf16)(o1[r4 * 4 + j] * inv);
    }
    *reinterpret_cast<bf16x4*>(&O[base + 8 * r4 + 4 * hi]) = p0;
    *reinterpret_cast<bf16x4*>(&O[base + 32 + 8 * r4 + 4 * hi]) = p1;
  }
}

extern "C" void kernel_launch(void* const* d_in, const int* in_sizes, int n_in,
                              void* d_out, int out_size, void* d_ws, size_t ws_size,
                              hipStream_t stream) {
  const float* x      = (const float*)d_in[0];
  const float* w_qkv  = (const float*)d_in[1];
  const float* b_qkv  = (const float*)d_in[2];
  const float* w_proj = (const float*)d_in[3];
  const float* b_proj = (const float*)d_in[4];
  const float* pos_in = (const float*)d_in[5];
  float* out = (float*)d_out;

  char* ws = (char*)d_ws;
  bf16* xb     = (bf16*)(ws);                         // 16 MB (reused as Ob)
  bf16* wqkvb  = (bf16*)(ws + 16777216);              //  6 MB
  bf16* wprojb = (bf16*)(ws + 23068672);              //  2 MB
  bf16* Qb     = (bf16*)(ws + 25165824);              // 16 MB
  bf16* Kb     = (bf16*)(ws + 41943040);              // 16 MB
  bf16* Vtb    = (bf16*)(ws + 58720256);              // 16 MB
  float* table = (float*)(ws + 75497472);             // 64 KB
  bf16* Ob = xb;

  static bool attr_done = false;
  if (!attr_done) {
    hipFuncSetAttribute((const void*)gemm_qkv8_kernel,
                        hipFuncAttributeMaxDynamicSharedMemorySize, 147456);
    hipFuncSetAttribute((const void*)gemm_proj8_kernel,
                        hipFuncAttributeMaxDynamicSharedMemorySize, 147456);
    attr_done = true;
  }

  const int nx = 8 * T_SEQ * DM, nwq = 3 * DM * DM, nwp = DM * DM;
  hope_bias_kernel<<<64, 256, 0, stream>>>(pos_in, table);
  cvt3_kernel<<<(nx + nwq + nwp) / 1024, 256, 0, stream>>>(
      x, xb, nx, w_qkv, wqkvb, nwq, w_proj, wprojb, nwp);

  gemm_qkv8_kernel<<<768, 512, 147456, stream>>>(xb, wqkvb, b_qkv, Qb, Kb, Vtb);
  attn_kernel<<<1024, 256, 0, stream>>>(Qb, Kb, Vtb, table, Ob);
  gemm_proj8_kernel<<<256, 512, 147456, stream>>>(Ob, wprojb, b_proj, out);
}